// Round 1
// baseline (1235.891 us; speedup 1.0000x reference)
//
#include <hip/hip_runtime.h>

#define NN 100000
#define NE 3200000
#define NG 128
#define BN_EPS 1e-5f

// ---------------- degree ----------------
__global__ void k_deg(const int* __restrict__ dst, int* __restrict__ deg, int E) {
    int e = blockIdx.x * blockDim.x + threadIdx.x;
    if (e < E) atomicAdd(&deg[dst[e]], 1);
}

// ---------------- 3-kernel exclusive scan over deg ----------------
__global__ void k_scan1(const int* __restrict__ deg, int* __restrict__ bsum, int N) {
    __shared__ int sm[256];
    int i = blockIdx.x * 256 + threadIdx.x;
    sm[threadIdx.x] = (i < N) ? deg[i] : 0;
    __syncthreads();
    for (int off = 128; off > 0; off >>= 1) {
        if (threadIdx.x < off) sm[threadIdx.x] += sm[threadIdx.x + off];
        __syncthreads();
    }
    if (threadIdx.x == 0) bsum[blockIdx.x] = sm[0];
}

__global__ void k_scan2(int* __restrict__ bsum, int NB) {  // 1 block x 512
    __shared__ int sm[512];
    int t = threadIdx.x;
    int v = (t < NB) ? bsum[t] : 0;
    sm[t] = v;
    __syncthreads();
    for (int off = 1; off < 512; off <<= 1) {
        int add = (t >= off) ? sm[t - off] : 0;
        __syncthreads();
        sm[t] += add;
        __syncthreads();
    }
    if (t < NB) bsum[t] = sm[t] - v;  // exclusive block offsets
}

__global__ void k_scan3(const int* __restrict__ deg, const int* __restrict__ bsum,
                        int* __restrict__ row_ptr, int* __restrict__ cursor,
                        float* __restrict__ deg_inv, int N, int E) {
    __shared__ int sm[256];
    int t = threadIdx.x;
    int i = blockIdx.x * 256 + t;
    int v = (i < N) ? deg[i] : 0;
    sm[t] = v;
    __syncthreads();
    for (int off = 1; off < 256; off <<= 1) {
        int add = (t >= off) ? sm[t - off] : 0;
        __syncthreads();
        sm[t] += add;
        __syncthreads();
    }
    if (i < N) {
        int excl = bsum[blockIdx.x] + sm[t] - v;
        row_ptr[i] = excl;
        cursor[i]  = excl;
        deg_inv[i] = 1.0f / fmaxf((float)v, 1.0f);
        if (i == N - 1) row_ptr[N] = E;
    }
}

// ---------------- CSR fill ----------------
__global__ void k_fill(const int* __restrict__ src, const int* __restrict__ dst,
                       int* __restrict__ cursor, int* __restrict__ csr_src, int E) {
    int e = blockIdx.x * blockDim.x + threadIdx.x;
    if (e < E) {
        int p = atomicAdd(&cursor[dst[e]], 1);
        csr_src[p] = src[e];
    }
}

// ---------------- layer 1 (IN_DIM=4): 16 lanes per node, edge-parallel ----------------
__global__ void __launch_bounds__(256) k_layer1(
    const float* __restrict__ x, const int* __restrict__ row_ptr,
    const int* __restrict__ csr_src, const float* __restrict__ deg_inv,
    const float* __restrict__ w1l, const float* __restrict__ b1,
    const float* __restrict__ w1r, float* __restrict__ h_pre, int N) {
    __shared__ float swl[256], swr[256], sb1[64];
    int tid = threadIdx.x;
    swl[tid] = w1l[tid];
    swr[tid] = w1r[tid];
    if (tid < 64) sb1[tid] = b1[tid];
    __syncthreads();

    int g = tid & 15, ni = tid >> 4;
    int n = blockIdx.x * 16 + ni;
    if (n >= N) return;

    int r0 = row_ptr[n], r1 = row_ptr[n + 1];
    float4 acc = make_float4(0.f, 0.f, 0.f, 0.f);
    for (int e = r0 + g; e < r1; e += 16) {
        int s = csr_src[e];
        float4 xv = ((const float4*)x)[s];
        acc.x += xv.x; acc.y += xv.y; acc.z += xv.z; acc.w += xv.w;
    }
    // reduce across the 16 lanes of this node group
    for (int m = 1; m < 16; m <<= 1) {
        acc.x += __shfl_xor(acc.x, m);
        acc.y += __shfl_xor(acc.y, m);
        acc.z += __shfl_xor(acc.z, m);
        acc.w += __shfl_xor(acc.w, m);
    }
    float di = deg_inv[n];
    float ax = acc.x * di, ay = acc.y * di, az = acc.z * di, aw = acc.w * di;
    float4 xs = ((const float4*)x)[n];

    float o[4];
#pragma unroll
    for (int m = 0; m < 4; m++) {
        int j = 4 * g + m;
        float s = sb1[j];
        s += ax * swl[j * 4 + 0] + ay * swl[j * 4 + 1] + az * swl[j * 4 + 2] + aw * swl[j * 4 + 3];
        s += xs.x * swr[j * 4 + 0] + xs.y * swr[j * 4 + 1] + xs.z * swr[j * 4 + 2] + xs.w * swr[j * 4 + 3];
        o[m] = s;
    }
    ((float4*)h_pre)[n * 16 + g] = make_float4(o[0], o[1], o[2], o[3]);
}

// ---------------- fused SAGE layer (HID=64): gather + 2 GEMMs ----------------
__global__ void __launch_bounds__(256) k_sage(
    const float* __restrict__ h_in, const int* __restrict__ row_ptr,
    const int* __restrict__ csr_src, const float* __restrict__ deg_inv,
    const float* __restrict__ wl, const float* __restrict__ bl,
    const float* __restrict__ wr, float* __restrict__ h_pre, int N) {
    __shared__ float wlT[64 * 68];  // transposed, stride 68 (16B-aligned rows, bank-spread)
    __shared__ float wrT[64 * 68];
    __shared__ float tA[16 * 68];
    __shared__ float tX[16 * 68];
    int tid = threadIdx.x;
    for (int idx = tid; idx < 4096; idx += 256) {
        int j = idx >> 6, k = idx & 63;
        wlT[k * 68 + j] = wl[idx];
        wrT[k * 68 + j] = wr[idx];
    }
    int g = tid & 15, ni = tid >> 4;
    int n = blockIdx.x * 16 + ni;
    bool valid = (n < N);

    float4 acc = make_float4(0.f, 0.f, 0.f, 0.f);
    float4 xs  = make_float4(0.f, 0.f, 0.f, 0.f);
    float di = 0.f;
    if (valid) {
        int r0 = row_ptr[n], r1 = row_ptr[n + 1];
        for (int e = r0; e < r1; ++e) {
            int s = csr_src[e];                    // uniform across 16 lanes -> broadcast
            float4 v = ((const float4*)h_in)[s * 16 + g];  // 16 lanes = 256B coalesced row
            acc.x += v.x; acc.y += v.y; acc.z += v.z; acc.w += v.w;
        }
        di = deg_inv[n];
        xs = ((const float4*)h_in)[n * 16 + g];
    }
    ((float4*)&tA[ni * 68])[g] = make_float4(acc.x * di, acc.y * di, acc.z * di, acc.w * di);
    ((float4*)&tX[ni * 68])[g] = xs;
    __syncthreads();

    float4 o = ((const float4*)bl)[g];
    const float* ta = &tA[ni * 68];
    const float* tx = &tX[ni * 68];
    for (int k = 0; k < 64; k++) {
        float a  = ta[k];
        float xv = tx[k];
        float4 wlv = ((const float4*)&wlT[k * 68])[g];
        float4 wrv = ((const float4*)&wrT[k * 68])[g];
        o.x += a * wlv.x + xv * wrv.x;
        o.y += a * wlv.y + xv * wrv.y;
        o.z += a * wlv.z + xv * wrv.z;
        o.w += a * wlv.w + xv * wrv.w;
    }
    if (valid) ((float4*)h_pre)[n * 16 + g] = o;
}

// ---------------- BN stats (sum, sumsq per channel) ----------------
__global__ void k_stats(const float* __restrict__ h, float* __restrict__ stats, int N) {
    int c = threadIdx.x & 63;
    int w = threadIdx.x >> 6;  // 0..3
    float s = 0.f, s2 = 0.f;
    for (int r = blockIdx.x * 4 + w; r < N; r += gridDim.x * 4) {
        float v = h[r * 64 + c];
        s += v;
        s2 += v * v;
    }
    __shared__ float sm[256], sm2[256];
    sm[threadIdx.x] = s;
    sm2[threadIdx.x] = s2;
    __syncthreads();
    if (threadIdx.x < 64) {
        float ts = sm[c] + sm[64 + c] + sm[128 + c] + sm[192 + c];
        float t2 = sm2[c] + sm2[64 + c] + sm2[128 + c] + sm2[192 + c];
        atomicAdd(&stats[c], ts);
        atomicAdd(&stats[64 + c], t2);
    }
}

__global__ void k_bnfinal(const float* __restrict__ stats, const float* __restrict__ gamma,
                          const float* __restrict__ beta, float* __restrict__ sb, int N) {
    int c = threadIdx.x;
    if (c < 64) {
        float m   = stats[c] / (float)N;
        float var = stats[64 + c] / (float)N - m * m;
        float sc  = gamma[c] * rsqrtf(var + BN_EPS);
        sb[c]      = sc;
        sb[64 + c] = beta[c] - m * sc;
    }
}

__global__ void k_bnrelu(const float* __restrict__ h_pre, const float* __restrict__ sb,
                         float* __restrict__ h, int N) {
    __shared__ float s_sc[64], s_bi[64];
    if (threadIdx.x < 64) {
        s_sc[threadIdx.x] = sb[threadIdx.x];
        s_bi[threadIdx.x] = sb[64 + threadIdx.x];
    }
    __syncthreads();
    int total = N * 16;
    for (int i = blockIdx.x * blockDim.x + threadIdx.x; i < total; i += gridDim.x * blockDim.x) {
        float4 v = ((const float4*)h_pre)[i];
        int c4 = (i & 15) * 4;
        v.x = fmaxf(v.x * s_sc[c4 + 0] + s_bi[c4 + 0], 0.f);
        v.y = fmaxf(v.y * s_sc[c4 + 1] + s_bi[c4 + 1], 0.f);
        v.z = fmaxf(v.z * s_sc[c4 + 2] + s_bi[c4 + 2], 0.f);
        v.w = fmaxf(v.w * s_sc[c4 + 3] + s_bi[c4 + 3], 0.f);
        ((float4*)h)[i] = v;
    }
}

// ---------------- pool: batch_ids sorted -> binary-search segment per block ----------------
__global__ void k_pool(const float* __restrict__ h, const int* __restrict__ batch,
                       float* __restrict__ pooled, int N) {
    int gph = blockIdx.x;
    int lo = 0, hi = N;
    while (lo < hi) { int mid = (lo + hi) >> 1; if (batch[mid] < gph) lo = mid + 1; else hi = mid; }
    int start = lo;
    hi = N;
    while (lo < hi) { int mid = (lo + hi) >> 1; if (batch[mid] < gph + 1) lo = mid + 1; else hi = mid; }
    int end = lo;

    int c = threadIdx.x & 63, w = threadIdx.x >> 6;
    float s = 0.f;
    for (int r = start + w; r < end; r += 4) s += h[r * 64 + c];
    __shared__ float sm[256];
    sm[threadIdx.x] = s;
    __syncthreads();
    if (threadIdx.x < 64) {
        float t = sm[c] + sm[64 + c] + sm[128 + c] + sm[192 + c];
        pooled[gph * 64 + c] = t / fmaxf((float)(end - start), 1.0f);
    }
}

// ---------------- MLP head ----------------
__global__ void k_head(const float* __restrict__ pooled,
                       const float* __restrict__ fc1w, const float* __restrict__ fc1b,
                       const float* __restrict__ fc2w, const float* __restrict__ fc2b,
                       float* __restrict__ out) {
    int gph = blockIdx.x;
    int j = threadIdx.x;  // 64
    __shared__ float pl[64], hid[64];
    pl[j] = pooled[gph * 64 + j];
    __syncthreads();
    float s = fc1b[j];
    for (int k = 0; k < 64; k++) s += pl[k] * fc1w[j * 64 + k];
    hid[j] = fmaxf(s, 0.f);
    __syncthreads();
    if (j < 2) {
        float o = fc2b[j];
        for (int k = 0; k < 64; k++) o += hid[k] * fc2w[j * 64 + k];
        out[gph * 2 + j] = o;
    }
}

extern "C" void kernel_launch(void* const* d_in, const int* in_sizes, int n_in,
                              void* d_out, int out_size, void* d_ws, size_t ws_size,
                              hipStream_t stream) {
    const float* x    = (const float*)d_in[0];
    const int* ei     = (const int*)d_in[1];
    const int* batch  = (const int*)d_in[2];
    const float* w1l  = (const float*)d_in[3];
    const float* b1   = (const float*)d_in[4];
    const float* w1r  = (const float*)d_in[5];
    const float* bn1g = (const float*)d_in[6];
    const float* bn1b = (const float*)d_in[7];
    const float* w2l  = (const float*)d_in[8];
    const float* b2   = (const float*)d_in[9];
    const float* w2r  = (const float*)d_in[10];
    const float* bn2g = (const float*)d_in[11];
    const float* bn2b = (const float*)d_in[12];
    const float* w3l  = (const float*)d_in[13];
    const float* b3   = (const float*)d_in[14];
    const float* w3r  = (const float*)d_in[15];
    const float* bn3g = (const float*)d_in[16];
    const float* bn3b = (const float*)d_in[17];
    const float* fc1w = (const float*)d_in[18];
    const float* fc1b = (const float*)d_in[19];
    const float* fc2w = (const float*)d_in[20];
    const float* fc2b = (const float*)d_in[21];
    float* out = (float*)d_out;

    const int N = NN, E = NE;
    const int* srcp = ei;
    const int* dstp = ei + E;

    char* ws = (char*)d_ws;
    size_t off = 0;
    auto alloc = [&](size_t bytes) -> char* {
        char* p = ws + off;
        off += (bytes + 255) & ~(size_t)255;
        return p;
    };
    int* csr_src   = (int*)alloc(sizeof(int) * E);
    float* hA      = (float*)alloc(sizeof(float) * N * 64);
    float* hB      = (float*)alloc(sizeof(float) * N * 64);
    int* deg       = (int*)alloc(sizeof(int) * N);
    int* row_ptr   = (int*)alloc(sizeof(int) * (N + 1));
    int* cursor    = (int*)alloc(sizeof(int) * N);
    float* deg_inv = (float*)alloc(sizeof(float) * N);
    int* bsum      = (int*)alloc(sizeof(int) * 512);
    float* stats   = (float*)alloc(sizeof(float) * 128);
    float* sb      = (float*)alloc(sizeof(float) * 128);
    float* pooled  = (float*)alloc(sizeof(float) * 64 * NG);

    const int NB1 = (N + 255) / 256;  // 391
    const int NBn = (N + 15) / 16;    // 6250

    hipMemsetAsync(deg, 0, sizeof(int) * N, stream);
    k_deg<<<(E + 255) / 256, 256, 0, stream>>>(dstp, deg, E);
    k_scan1<<<NB1, 256, 0, stream>>>(deg, bsum, N);
    k_scan2<<<1, 512, 0, stream>>>(bsum, NB1);
    k_scan3<<<NB1, 256, 0, stream>>>(deg, bsum, row_ptr, cursor, deg_inv, N, E);
    k_fill<<<(E + 255) / 256, 256, 0, stream>>>(srcp, dstp, cursor, csr_src, E);

    // layer 1: x -> hB (pre-BN), BN+ReLU -> hA
    k_layer1<<<NBn, 256, 0, stream>>>(x, row_ptr, csr_src, deg_inv, w1l, b1, w1r, hB, N);
    hipMemsetAsync(stats, 0, sizeof(float) * 128, stream);
    k_stats<<<200, 256, 0, stream>>>(hB, stats, N);
    k_bnfinal<<<1, 64, 0, stream>>>(stats, bn1g, bn1b, sb, N);
    k_bnrelu<<<1024, 256, 0, stream>>>(hB, sb, hA, N);

    // layer 2: hA -> hB, BN+ReLU -> hA
    k_sage<<<NBn, 256, 0, stream>>>(hA, row_ptr, csr_src, deg_inv, w2l, b2, w2r, hB, N);
    hipMemsetAsync(stats, 0, sizeof(float) * 128, stream);
    k_stats<<<200, 256, 0, stream>>>(hB, stats, N);
    k_bnfinal<<<1, 64, 0, stream>>>(stats, bn2g, bn2b, sb, N);
    k_bnrelu<<<1024, 256, 0, stream>>>(hB, sb, hA, N);

    // layer 3: hA -> hB, BN+ReLU -> hA
    k_sage<<<NBn, 256, 0, stream>>>(hA, row_ptr, csr_src, deg_inv, w3l, b3, w3r, hB, N);
    hipMemsetAsync(stats, 0, sizeof(float) * 128, stream);
    k_stats<<<200, 256, 0, stream>>>(hB, stats, N);
    k_bnfinal<<<1, 64, 0, stream>>>(stats, bn3g, bn3b, sb, N);
    k_bnrelu<<<1024, 256, 0, stream>>>(hB, sb, hA, N);

    k_pool<<<NG, 256, 0, stream>>>(hA, batch, pooled, N);
    k_head<<<NG, 64, 0, stream>>>(pooled, fc1w, fc1b, fc2w, fc2b, out);
}

// Round 2
// 921.724 us; speedup vs baseline: 1.3408x; 1.3408x over previous
//
#include <hip/hip_runtime.h>

#define NN 100000
#define NE 3200000
#define NG 128
#define BN_EPS 1e-5f

#define NBUK 782          // ceil(100000 / 128)
#define BSHIFT 7          // bucket = dst >> 7 (128 nodes per bucket)
#define BCAP 6144         // slab capacity per bucket (mean 4096, +32 sigma)

// ---------------- bucketed edge scatter (counting-sort level 1) ----------------
// 256 blocks x 512 threads; block b owns edges [b*12500, (b+1)*12500)
__global__ void __launch_bounds__(512) k_scatter(
    const int* __restrict__ src, const int* __restrict__ dst,
    int* __restrict__ slab_cursor, unsigned int* __restrict__ slab, int E) {
    __shared__ int hist[NBUK + 2];
    __shared__ int cbase[NBUK + 2];
    int tid = threadIdx.x;
    int eBeg = blockIdx.x * 12500;
    int eEnd = min(eBeg + 12500, E);

    for (int t = tid; t < NBUK; t += 512) hist[t] = 0;
    __syncthreads();
    // pass i: local histogram
    for (int e = eBeg + tid; e < eEnd; e += 512) {
        int b = dst[e] >> BSHIFT;
        atomicAdd(&hist[b], 1);
    }
    __syncthreads();
    // reserve contiguous chunks in each bucket's slab
    for (int t = tid; t < NBUK; t += 512) {
        int c = hist[t];
        cbase[t] = (c > 0) ? atomicAdd(&slab_cursor[t], c) : 0;
    }
    __syncthreads();
    for (int t = tid; t < NBUK; t += 512) hist[t] = 0;  // reuse as rank counter
    __syncthreads();
    // pass ii: scatter packed (src<<7 | local_dst) into reserved chunks
    for (int e = eBeg + tid; e < eEnd; e += 512) {
        int d = dst[e];
        int b = d >> BSHIFT;
        int r = atomicAdd(&hist[b], 1);
        int pos = cbase[b] + r;
        if (pos < BCAP) slab[(size_t)b * BCAP + pos] = ((unsigned)src[e] << BSHIFT) | (unsigned)(d & 127);
    }
}

// ---------------- scan 782 bucket counts -> bucket CSR bases ----------------
__global__ void k_bucket_scan(const int* __restrict__ slab_cursor,
                              int* __restrict__ bucket_base, int* __restrict__ row_ptr) {
    __shared__ int sm[1024];
    int t = threadIdx.x;
    int c = (t < NBUK) ? min(slab_cursor[t], BCAP) : 0;
    sm[t] = c;
    __syncthreads();
    for (int off = 1; off < 1024; off <<= 1) {
        int add = (t >= off) ? sm[t - off] : 0;
        __syncthreads();
        sm[t] += add;
        __syncthreads();
    }
    if (t < NBUK) {
        bucket_base[t] = sm[t] - c;  // exclusive
        if (t == NBUK - 1) row_ptr[NN] = sm[t];
    }
}

// ---------------- per-bucket exact CSR build (counting-sort level 2) ----------------
// 782 blocks x 256 threads; bucket b covers nodes [b*128, b*128+128)
__global__ void __launch_bounds__(256) k_bucket_csr(
    const unsigned int* __restrict__ slab, const int* __restrict__ slab_cursor,
    const int* __restrict__ bucket_base, int* __restrict__ row_ptr,
    float* __restrict__ deg_inv, int* __restrict__ csr_src) {
    __shared__ int sdeg[128];
    __shared__ int sscan[128];
    __shared__ int slcur[128];
    int tid = threadIdx.x;
    int b = blockIdx.x;
    int lo = b << BSHIFT;
    int cnt = min(slab_cursor[b], BCAP);
    const unsigned int* sl = slab + (size_t)b * BCAP;

    if (tid < 128) sdeg[tid] = 0;
    __syncthreads();
    for (int k = tid; k < cnt; k += 256) {
        atomicAdd(&sdeg[sl[k] & 127], 1);
    }
    __syncthreads();
    int v = (tid < 128) ? sdeg[tid] : 0;
    if (tid < 128) sscan[tid] = v;
    __syncthreads();
    for (int off = 1; off < 128; off <<= 1) {
        int add = 0;
        if (tid < 128 && tid >= off) add = sscan[tid - off];
        __syncthreads();
        if (tid < 128) sscan[tid] += add;
        __syncthreads();
    }
    int base = bucket_base[b];
    if (tid < 128) {
        int excl = sscan[tid] - v;
        int n = lo + tid;
        if (n < NN) {
            row_ptr[n] = base + excl;
            deg_inv[n] = 1.0f / fmaxf((float)v, 1.0f);
        }
        slcur[tid] = base + excl;
    }
    __syncthreads();
    for (int k = tid; k < cnt; k += 256) {
        unsigned int p = sl[k];
        int pos = atomicAdd(&slcur[p & 127], 1);
        csr_src[pos] = (int)(p >> BSHIFT);
    }
}

// ---------------- layer 1 (IN_DIM=4): 16 lanes per node, edge-parallel ----------------
__global__ void __launch_bounds__(256) k_layer1(
    const float* __restrict__ x, const int* __restrict__ row_ptr,
    const int* __restrict__ csr_src, const float* __restrict__ deg_inv,
    const float* __restrict__ w1l, const float* __restrict__ b1,
    const float* __restrict__ w1r, float* __restrict__ h_pre, int N) {
    __shared__ float swl[256], swr[256], sb1[64];
    int tid = threadIdx.x;
    swl[tid] = w1l[tid];
    swr[tid] = w1r[tid];
    if (tid < 64) sb1[tid] = b1[tid];
    __syncthreads();

    int g = tid & 15, ni = tid >> 4;
    int n = blockIdx.x * 16 + ni;
    if (n >= N) return;

    int r0 = row_ptr[n], r1 = row_ptr[n + 1];
    float4 acc = make_float4(0.f, 0.f, 0.f, 0.f);
    for (int e = r0 + g; e < r1; e += 16) {
        int s = csr_src[e];
        float4 xv = ((const float4*)x)[s];
        acc.x += xv.x; acc.y += xv.y; acc.z += xv.z; acc.w += xv.w;
    }
    for (int m = 1; m < 16; m <<= 1) {
        acc.x += __shfl_xor(acc.x, m);
        acc.y += __shfl_xor(acc.y, m);
        acc.z += __shfl_xor(acc.z, m);
        acc.w += __shfl_xor(acc.w, m);
    }
    float di = deg_inv[n];
    float ax = acc.x * di, ay = acc.y * di, az = acc.z * di, aw = acc.w * di;
    float4 xs = ((const float4*)x)[n];

    float o[4];
#pragma unroll
    for (int m = 0; m < 4; m++) {
        int j = 4 * g + m;
        float s = sb1[j];
        s += ax * swl[j * 4 + 0] + ay * swl[j * 4 + 1] + az * swl[j * 4 + 2] + aw * swl[j * 4 + 3];
        s += xs.x * swr[j * 4 + 0] + xs.y * swr[j * 4 + 1] + xs.z * swr[j * 4 + 2] + xs.w * swr[j * 4 + 3];
        o[m] = s;
    }
    ((float4*)h_pre)[n * 16 + g] = make_float4(o[0], o[1], o[2], o[3]);
}

// ---------------- fused SAGE layer (HID=64): gather + 2 GEMMs ----------------
__global__ void __launch_bounds__(256) k_sage(
    const float* __restrict__ h_in, const int* __restrict__ row_ptr,
    const int* __restrict__ csr_src, const float* __restrict__ deg_inv,
    const float* __restrict__ wl, const float* __restrict__ bl,
    const float* __restrict__ wr, float* __restrict__ h_pre, int N) {
    __shared__ float wlT[64 * 68];
    __shared__ float wrT[64 * 68];
    __shared__ float tA[16 * 68];
    __shared__ float tX[16 * 68];
    int tid = threadIdx.x;
    for (int idx = tid; idx < 4096; idx += 256) {
        int j = idx >> 6, k = idx & 63;
        wlT[k * 68 + j] = wl[idx];
        wrT[k * 68 + j] = wr[idx];
    }
    int g = tid & 15, ni = tid >> 4;
    int n = blockIdx.x * 16 + ni;
    bool valid = (n < N);

    float4 acc = make_float4(0.f, 0.f, 0.f, 0.f);
    float4 xs  = make_float4(0.f, 0.f, 0.f, 0.f);
    float di = 0.f;
    if (valid) {
        int r0 = row_ptr[n], r1 = row_ptr[n + 1];
        for (int e = r0; e < r1; ++e) {
            int s = csr_src[e];
            float4 v = ((const float4*)h_in)[s * 16 + g];
            acc.x += v.x; acc.y += v.y; acc.z += v.z; acc.w += v.w;
        }
        di = deg_inv[n];
        xs = ((const float4*)h_in)[n * 16 + g];
    }
    ((float4*)&tA[ni * 68])[g] = make_float4(acc.x * di, acc.y * di, acc.z * di, acc.w * di);
    ((float4*)&tX[ni * 68])[g] = xs;
    __syncthreads();

    float4 o = ((const float4*)bl)[g];
    const float* ta = &tA[ni * 68];
    const float* tx = &tX[ni * 68];
    for (int k = 0; k < 64; k++) {
        float a  = ta[k];
        float xv = tx[k];
        float4 wlv = ((const float4*)&wlT[k * 68])[g];
        float4 wrv = ((const float4*)&wrT[k * 68])[g];
        o.x += a * wlv.x + xv * wrv.x;
        o.y += a * wlv.y + xv * wrv.y;
        o.z += a * wlv.z + xv * wrv.z;
        o.w += a * wlv.w + xv * wrv.w;
    }
    if (valid) ((float4*)h_pre)[n * 16 + g] = o;
}

// ---------------- BN stats (sum, sumsq per channel) ----------------
__global__ void k_stats(const float* __restrict__ h, float* __restrict__ stats, int N) {
    int c = threadIdx.x & 63;
    int w = threadIdx.x >> 6;
    float s = 0.f, s2 = 0.f;
    for (int r = blockIdx.x * 4 + w; r < N; r += gridDim.x * 4) {
        float v = h[r * 64 + c];
        s += v;
        s2 += v * v;
    }
    __shared__ float sm[256], sm2[256];
    sm[threadIdx.x] = s;
    sm2[threadIdx.x] = s2;
    __syncthreads();
    if (threadIdx.x < 64) {
        float ts = sm[c] + sm[64 + c] + sm[128 + c] + sm[192 + c];
        float t2 = sm2[c] + sm2[64 + c] + sm2[128 + c] + sm2[192 + c];
        atomicAdd(&stats[c], ts);
        atomicAdd(&stats[64 + c], t2);
    }
}

__global__ void k_bnfinal(const float* __restrict__ stats, const float* __restrict__ gamma,
                          const float* __restrict__ beta, float* __restrict__ sb, int N) {
    int c = threadIdx.x;
    if (c < 64) {
        float m   = stats[c] / (float)N;
        float var = stats[64 + c] / (float)N - m * m;
        float sc  = gamma[c] * rsqrtf(var + BN_EPS);
        sb[c]      = sc;
        sb[64 + c] = beta[c] - m * sc;
    }
}

__global__ void k_bnrelu(const float* __restrict__ h_pre, const float* __restrict__ sb,
                         float* __restrict__ h, int N) {
    __shared__ float s_sc[64], s_bi[64];
    if (threadIdx.x < 64) {
        s_sc[threadIdx.x] = sb[threadIdx.x];
        s_bi[threadIdx.x] = sb[64 + threadIdx.x];
    }
    __syncthreads();
    int total = N * 16;
    for (int i = blockIdx.x * blockDim.x + threadIdx.x; i < total; i += gridDim.x * blockDim.x) {
        float4 v = ((const float4*)h_pre)[i];
        int c4 = (i & 15) * 4;
        v.x = fmaxf(v.x * s_sc[c4 + 0] + s_bi[c4 + 0], 0.f);
        v.y = fmaxf(v.y * s_sc[c4 + 1] + s_bi[c4 + 1], 0.f);
        v.z = fmaxf(v.z * s_sc[c4 + 2] + s_bi[c4 + 2], 0.f);
        v.w = fmaxf(v.w * s_sc[c4 + 3] + s_bi[c4 + 3], 0.f);
        ((float4*)h)[i] = v;
    }
}

// ---------------- pool ----------------
__global__ void k_pool(const float* __restrict__ h, const int* __restrict__ batch,
                       float* __restrict__ pooled, int N) {
    int gph = blockIdx.x;
    int lo = 0, hi = N;
    while (lo < hi) { int mid = (lo + hi) >> 1; if (batch[mid] < gph) lo = mid + 1; else hi = mid; }
    int start = lo;
    hi = N;
    while (lo < hi) { int mid = (lo + hi) >> 1; if (batch[mid] < gph + 1) lo = mid + 1; else hi = mid; }
    int end = lo;

    int c = threadIdx.x & 63, w = threadIdx.x >> 6;
    float s = 0.f;
    for (int r = start + w; r < end; r += 4) s += h[r * 64 + c];
    __shared__ float sm[256];
    sm[threadIdx.x] = s;
    __syncthreads();
    if (threadIdx.x < 64) {
        float t = sm[c] + sm[64 + c] + sm[128 + c] + sm[192 + c];
        pooled[gph * 64 + c] = t / fmaxf((float)(end - start), 1.0f);
    }
}

// ---------------- MLP head ----------------
__global__ void k_head(const float* __restrict__ pooled,
                       const float* __restrict__ fc1w, const float* __restrict__ fc1b,
                       const float* __restrict__ fc2w, const float* __restrict__ fc2b,
                       float* __restrict__ out) {
    int gph = blockIdx.x;
    int j = threadIdx.x;
    __shared__ float pl[64], hid[64];
    pl[j] = pooled[gph * 64 + j];
    __syncthreads();
    float s = fc1b[j];
    for (int k = 0; k < 64; k++) s += pl[k] * fc1w[j * 64 + k];
    hid[j] = fmaxf(s, 0.f);
    __syncthreads();
    if (j < 2) {
        float o = fc2b[j];
        for (int k = 0; k < 64; k++) o += hid[k] * fc2w[j * 64 + k];
        out[gph * 2 + j] = o;
    }
}

extern "C" void kernel_launch(void* const* d_in, const int* in_sizes, int n_in,
                              void* d_out, int out_size, void* d_ws, size_t ws_size,
                              hipStream_t stream) {
    const float* x    = (const float*)d_in[0];
    const int* ei     = (const int*)d_in[1];
    const int* batch  = (const int*)d_in[2];
    const float* w1l  = (const float*)d_in[3];
    const float* b1   = (const float*)d_in[4];
    const float* w1r  = (const float*)d_in[5];
    const float* bn1g = (const float*)d_in[6];
    const float* bn1b = (const float*)d_in[7];
    const float* w2l  = (const float*)d_in[8];
    const float* b2   = (const float*)d_in[9];
    const float* w2r  = (const float*)d_in[10];
    const float* bn2g = (const float*)d_in[11];
    const float* bn2b = (const float*)d_in[12];
    const float* w3l  = (const float*)d_in[13];
    const float* b3   = (const float*)d_in[14];
    const float* w3r  = (const float*)d_in[15];
    const float* bn3g = (const float*)d_in[16];
    const float* bn3b = (const float*)d_in[17];
    const float* fc1w = (const float*)d_in[18];
    const float* fc1b = (const float*)d_in[19];
    const float* fc2w = (const float*)d_in[20];
    const float* fc2b = (const float*)d_in[21];
    float* out = (float*)d_out;

    const int N = NN, E = NE;
    const int* srcp = ei;
    const int* dstp = ei + E;

    char* ws = (char*)d_ws;
    size_t off = 0;
    auto alloc = [&](size_t bytes) -> char* {
        char* p = ws + off;
        off += (bytes + 255) & ~(size_t)255;
        return p;
    };
    int* csr_src     = (int*)alloc(sizeof(int) * E);
    float* hA        = (float*)alloc(sizeof(float) * N * 64);
    float* hB        = (float*)alloc(sizeof(float) * N * 64);
    unsigned int* slab = (unsigned int*)alloc(sizeof(unsigned int) * (size_t)NBUK * BCAP);
    int* slab_cursor = (int*)alloc(sizeof(int) * NBUK);
    int* bucket_base = (int*)alloc(sizeof(int) * NBUK);
    int* row_ptr     = (int*)alloc(sizeof(int) * (N + 1));
    float* deg_inv   = (float*)alloc(sizeof(float) * N);
    float* stats     = (float*)alloc(sizeof(float) * 128);
    float* sb        = (float*)alloc(sizeof(float) * 128);
    float* pooled    = (float*)alloc(sizeof(float) * 64 * NG);

    const int NBn = (N + 15) / 16;  // 6250

    // ---- CSR build: bucketed counting sort, ~200k global atomics total ----
    hipMemsetAsync(slab_cursor, 0, sizeof(int) * NBUK, stream);
    k_scatter<<<256, 512, 0, stream>>>(srcp, dstp, slab_cursor, slab, E);
    k_bucket_scan<<<1, 1024, 0, stream>>>(slab_cursor, bucket_base, row_ptr);
    k_bucket_csr<<<NBUK, 256, 0, stream>>>(slab, slab_cursor, bucket_base, row_ptr, deg_inv, csr_src);

    // layer 1: x -> hB (pre-BN), BN+ReLU -> hA
    k_layer1<<<NBn, 256, 0, stream>>>(x, row_ptr, csr_src, deg_inv, w1l, b1, w1r, hB, N);
    hipMemsetAsync(stats, 0, sizeof(float) * 128, stream);
    k_stats<<<200, 256, 0, stream>>>(hB, stats, N);
    k_bnfinal<<<1, 64, 0, stream>>>(stats, bn1g, bn1b, sb, N);
    k_bnrelu<<<1024, 256, 0, stream>>>(hB, sb, hA, N);

    // layer 2
    k_sage<<<NBn, 256, 0, stream>>>(hA, row_ptr, csr_src, deg_inv, w2l, b2, w2r, hB, N);
    hipMemsetAsync(stats, 0, sizeof(float) * 128, stream);
    k_stats<<<200, 256, 0, stream>>>(hB, stats, N);
    k_bnfinal<<<1, 64, 0, stream>>>(stats, bn2g, bn2b, sb, N);
    k_bnrelu<<<1024, 256, 0, stream>>>(hB, sb, hA, N);

    // layer 3
    k_sage<<<NBn, 256, 0, stream>>>(hA, row_ptr, csr_src, deg_inv, w3l, b3, w3r, hB, N);
    hipMemsetAsync(stats, 0, sizeof(float) * 128, stream);
    k_stats<<<200, 256, 0, stream>>>(hB, stats, N);
    k_bnfinal<<<1, 64, 0, stream>>>(stats, bn3g, bn3b, sb, N);
    k_bnrelu<<<1024, 256, 0, stream>>>(hB, sb, hA, N);

    k_pool<<<NG, 256, 0, stream>>>(hA, batch, pooled, N);
    k_head<<<NG, 64, 0, stream>>>(pooled, fc1w, fc1b, fc2w, fc2b, out);
}

// Round 3
// 711.817 us; speedup vs baseline: 1.7362x; 1.2949x over previous
//
#include <hip/hip_runtime.h>
#include <hip/hip_fp16.h>

#define NN 100000
#define NE 3200000
#define NG 128
#define BN_EPS 1e-5f

#define NBUK 782          // ceil(100000 / 128)
#define BSHIFT 7          // bucket = dst >> 7 (128 nodes per bucket)
#define BCAP 6144         // slab capacity per bucket (mean 4096, +32 sigma)

// ---------------- bucketed edge scatter (counting-sort level 1) ----------------
__global__ void __launch_bounds__(512) k_scatter(
    const int* __restrict__ src, const int* __restrict__ dst,
    int* __restrict__ slab_cursor, unsigned int* __restrict__ slab, int E) {
    __shared__ int hist[NBUK + 2];
    __shared__ int cbase[NBUK + 2];
    int tid = threadIdx.x;
    int eBeg = blockIdx.x * 12500;
    int eEnd = min(eBeg + 12500, E);

    for (int t = tid; t < NBUK; t += 512) hist[t] = 0;
    __syncthreads();
    for (int e = eBeg + tid; e < eEnd; e += 512) {
        int b = dst[e] >> BSHIFT;
        atomicAdd(&hist[b], 1);
    }
    __syncthreads();
    for (int t = tid; t < NBUK; t += 512) {
        int c = hist[t];
        cbase[t] = (c > 0) ? atomicAdd(&slab_cursor[t], c) : 0;
    }
    __syncthreads();
    for (int t = tid; t < NBUK; t += 512) hist[t] = 0;
    __syncthreads();
    for (int e = eBeg + tid; e < eEnd; e += 512) {
        int d = dst[e];
        int b = d >> BSHIFT;
        int r = atomicAdd(&hist[b], 1);
        int pos = cbase[b] + r;
        if (pos < BCAP) slab[(size_t)b * BCAP + pos] = ((unsigned)src[e] << BSHIFT) | (unsigned)(d & 127);
    }
}

// ---------------- scan 782 bucket counts -> bucket CSR bases ----------------
__global__ void k_bucket_scan(const int* __restrict__ slab_cursor,
                              int* __restrict__ bucket_base, int* __restrict__ row_ptr) {
    __shared__ int sm[1024];
    int t = threadIdx.x;
    int c = (t < NBUK) ? min(slab_cursor[t], BCAP) : 0;
    sm[t] = c;
    __syncthreads();
    for (int off = 1; off < 1024; off <<= 1) {
        int add = (t >= off) ? sm[t - off] : 0;
        __syncthreads();
        sm[t] += add;
        __syncthreads();
    }
    if (t < NBUK) {
        bucket_base[t] = sm[t] - c;
        if (t == NBUK - 1) row_ptr[NN] = sm[t];
    }
}

// ---------------- per-bucket exact CSR build (counting-sort level 2) ----------------
__global__ void __launch_bounds__(256) k_bucket_csr(
    const unsigned int* __restrict__ slab, const int* __restrict__ slab_cursor,
    const int* __restrict__ bucket_base, int* __restrict__ row_ptr,
    float* __restrict__ deg_inv, int* __restrict__ csr_src) {
    __shared__ int sdeg[128];
    __shared__ int sscan[128];
    __shared__ int slcur[128];
    int tid = threadIdx.x;
    int b = blockIdx.x;
    int lo = b << BSHIFT;
    int cnt = min(slab_cursor[b], BCAP);
    const unsigned int* sl = slab + (size_t)b * BCAP;

    if (tid < 128) sdeg[tid] = 0;
    __syncthreads();
    for (int k = tid; k < cnt; k += 256) {
        atomicAdd(&sdeg[sl[k] & 127], 1);
    }
    __syncthreads();
    int v = (tid < 128) ? sdeg[tid] : 0;
    if (tid < 128) sscan[tid] = v;
    __syncthreads();
    for (int off = 1; off < 128; off <<= 1) {
        int add = 0;
        if (tid < 128 && tid >= off) add = sscan[tid - off];
        __syncthreads();
        if (tid < 128) sscan[tid] += add;
        __syncthreads();
    }
    int base = bucket_base[b];
    if (tid < 128) {
        int excl = sscan[tid] - v;
        int n = lo + tid;
        if (n < NN) {
            row_ptr[n] = base + excl;
            deg_inv[n] = 1.0f / fmaxf((float)v, 1.0f);
        }
        slcur[tid] = base + excl;
    }
    __syncthreads();
    for (int k = tid; k < cnt; k += 256) {
        unsigned int p = sl[k];
        int pos = atomicAdd(&slcur[p & 127], 1);
        csr_src[pos] = (int)(p >> BSHIFT);
    }
}

// ---------------- layer 1 (IN_DIM=4) ----------------
__global__ void __launch_bounds__(256) k_layer1(
    const float* __restrict__ x, const int* __restrict__ row_ptr,
    const int* __restrict__ csr_src, const float* __restrict__ deg_inv,
    const float* __restrict__ w1l, const float* __restrict__ b1,
    const float* __restrict__ w1r, float* __restrict__ h_pre, int N) {
    __shared__ float swl[256], swr[256], sb1[64];
    int tid = threadIdx.x;
    swl[tid] = w1l[tid];
    swr[tid] = w1r[tid];
    if (tid < 64) sb1[tid] = b1[tid];
    __syncthreads();

    int g = tid & 15, ni = tid >> 4;
    int n = blockIdx.x * 16 + ni;
    if (n >= N) return;

    int r0 = row_ptr[n], r1 = row_ptr[n + 1];
    float4 acc = make_float4(0.f, 0.f, 0.f, 0.f);
    for (int e = r0 + g; e < r1; e += 16) {
        int s = csr_src[e];
        float4 xv = ((const float4*)x)[s];
        acc.x += xv.x; acc.y += xv.y; acc.z += xv.z; acc.w += xv.w;
    }
    for (int m = 1; m < 16; m <<= 1) {
        acc.x += __shfl_xor(acc.x, m);
        acc.y += __shfl_xor(acc.y, m);
        acc.z += __shfl_xor(acc.z, m);
        acc.w += __shfl_xor(acc.w, m);
    }
    float di = deg_inv[n];
    float ax = acc.x * di, ay = acc.y * di, az = acc.z * di, aw = acc.w * di;
    float4 xs = ((const float4*)x)[n];

    float o[4];
#pragma unroll
    for (int m = 0; m < 4; m++) {
        int j = 4 * g + m;
        float s = sb1[j];
        s += ax * swl[j * 4 + 0] + ay * swl[j * 4 + 1] + az * swl[j * 4 + 2] + aw * swl[j * 4 + 3];
        s += xs.x * swr[j * 4 + 0] + xs.y * swr[j * 4 + 1] + xs.z * swr[j * 4 + 2] + xs.w * swr[j * 4 + 3];
        o[m] = s;
    }
    ((float4*)h_pre)[n * 16 + g] = make_float4(o[0], o[1], o[2], o[3]);
}

// ---------------- fused SAGE layer: fp16 gather + 2 GEMMs ----------------
// 512 threads, 32 nodes/block. LDS: 2x17408 (weights) + 2x8704 (tiles) = 52.2 KB
// -> 3 blocks/CU, 24 waves/CU (75% occ). Gather row = 128 B fp16.
__global__ void __launch_bounds__(512) k_sage(
    const __half* __restrict__ h_in, const int* __restrict__ row_ptr,
    const int* __restrict__ csr_src, const float* __restrict__ deg_inv,
    const float* __restrict__ wl, const float* __restrict__ bl,
    const float* __restrict__ wr, float* __restrict__ h_pre, int N) {
    __shared__ float wlT[64 * 68];
    __shared__ float wrT[64 * 68];
    __shared__ float tA[32 * 68];
    __shared__ float tX[32 * 68];
    int tid = threadIdx.x;
    for (int idx = tid; idx < 4096; idx += 512) {
        int j = idx >> 6, k = idx & 63;
        wlT[k * 68 + j] = wl[idx];
        wrT[k * 68 + j] = wr[idx];
    }
    int g = tid & 15, ni = tid >> 4;      // ni in [0,32)
    int n = blockIdx.x * 32 + ni;         // N = 3125*32 exactly

    float ax = 0.f, ay = 0.f, az = 0.f, aw = 0.f;
    int r0 = row_ptr[n], r1 = row_ptr[n + 1];
    for (int e = r0; e < r1; ++e) {
        int s = csr_src[e];
        uint2 raw = ((const uint2*)h_in)[(size_t)s * 16 + g];  // 8B = 4 halfs
        float2 f0 = __half22float2(*(__half2*)&raw.x);
        float2 f1 = __half22float2(*(__half2*)&raw.y);
        ax += f0.x; ay += f0.y; az += f1.x; aw += f1.y;
    }
    float di = deg_inv[n];
    uint2 rs = ((const uint2*)h_in)[(size_t)n * 16 + g];
    float2 s0 = __half22float2(*(__half2*)&rs.x);
    float2 s1 = __half22float2(*(__half2*)&rs.y);

    ((float4*)&tA[ni * 68])[g] = make_float4(ax * di, ay * di, az * di, aw * di);
    ((float4*)&tX[ni * 68])[g] = make_float4(s0.x, s0.y, s1.x, s1.y);
    __syncthreads();

    float4 o = ((const float4*)bl)[g];
    const float* ta = &tA[ni * 68];
    const float* tx = &tX[ni * 68];
    for (int k = 0; k < 64; k++) {
        float a  = ta[k];
        float xv = tx[k];
        float4 wlv = ((const float4*)&wlT[k * 68])[g];
        float4 wrv = ((const float4*)&wrT[k * 68])[g];
        o.x += a * wlv.x + xv * wrv.x;
        o.y += a * wlv.y + xv * wrv.y;
        o.z += a * wlv.z + xv * wrv.z;
        o.w += a * wlv.w + xv * wrv.w;
    }
    ((float4*)h_pre)[(size_t)n * 16 + g] = o;
}

// ---------------- BN stats (sum, sumsq per channel) ----------------
__global__ void k_stats(const float* __restrict__ h, float* __restrict__ stats, int N) {
    int c = threadIdx.x & 63;
    int w = threadIdx.x >> 6;
    float s = 0.f, s2 = 0.f;
    for (int r = blockIdx.x * 4 + w; r < N; r += gridDim.x * 4) {
        float v = h[r * 64 + c];
        s += v;
        s2 += v * v;
    }
    __shared__ float sm[256], sm2[256];
    sm[threadIdx.x] = s;
    sm2[threadIdx.x] = s2;
    __syncthreads();
    if (threadIdx.x < 64) {
        float ts = sm[c] + sm[64 + c] + sm[128 + c] + sm[192 + c];
        float t2 = sm2[c] + sm2[64 + c] + sm2[128 + c] + sm2[192 + c];
        atomicAdd(&stats[c], ts);
        atomicAdd(&stats[64 + c], t2);
    }
}

__global__ void k_bnfinal(const float* __restrict__ stats, const float* __restrict__ gamma,
                          const float* __restrict__ beta, float* __restrict__ sb, int N) {
    int c = threadIdx.x;
    if (c < 64) {
        float m   = stats[c] / (float)N;
        float var = stats[64 + c] / (float)N - m * m;
        float sc  = gamma[c] * rsqrtf(var + BN_EPS);
        sb[c]      = sc;
        sb[64 + c] = beta[c] - m * sc;
    }
}

// BN+ReLU -> fp16 table (feeds next layer's gather / final pool)
__global__ void k_bnrelu_h(const float* __restrict__ h_pre, const float* __restrict__ sb,
                           __half* __restrict__ h, int N) {
    __shared__ float s_sc[64], s_bi[64];
    if (threadIdx.x < 64) {
        s_sc[threadIdx.x] = sb[threadIdx.x];
        s_bi[threadIdx.x] = sb[64 + threadIdx.x];
    }
    __syncthreads();
    int total = N * 16;
    for (int i = blockIdx.x * blockDim.x + threadIdx.x; i < total; i += gridDim.x * blockDim.x) {
        float4 v = ((const float4*)h_pre)[i];
        int c4 = (i & 15) * 4;
        v.x = fmaxf(v.x * s_sc[c4 + 0] + s_bi[c4 + 0], 0.f);
        v.y = fmaxf(v.y * s_sc[c4 + 1] + s_bi[c4 + 1], 0.f);
        v.z = fmaxf(v.z * s_sc[c4 + 2] + s_bi[c4 + 2], 0.f);
        v.w = fmaxf(v.w * s_sc[c4 + 3] + s_bi[c4 + 3], 0.f);
        __half2 p0 = __floats2half2_rn(v.x, v.y);
        __half2 p1 = __floats2half2_rn(v.z, v.w);
        uint2 o;
        o.x = *(unsigned int*)&p0;
        o.y = *(unsigned int*)&p1;
        ((uint2*)h)[i] = o;
    }
}

// ---------------- pool (reads fp16 table, sums fp32) ----------------
__global__ void k_pool(const __half* __restrict__ h, const int* __restrict__ batch,
                       float* __restrict__ pooled, int N) {
    int gph = blockIdx.x;
    int lo = 0, hi = N;
    while (lo < hi) { int mid = (lo + hi) >> 1; if (batch[mid] < gph) lo = mid + 1; else hi = mid; }
    int start = lo;
    hi = N;
    while (lo < hi) { int mid = (lo + hi) >> 1; if (batch[mid] < gph + 1) lo = mid + 1; else hi = mid; }
    int end = lo;

    int c = threadIdx.x & 63, w = threadIdx.x >> 6;
    float s = 0.f;
    for (int r = start + w; r < end; r += 4) s += __half2float(h[r * 64 + c]);
    __shared__ float sm[256];
    sm[threadIdx.x] = s;
    __syncthreads();
    if (threadIdx.x < 64) {
        float t = sm[c] + sm[64 + c] + sm[128 + c] + sm[192 + c];
        pooled[gph * 64 + c] = t / fmaxf((float)(end - start), 1.0f);
    }
}

// ---------------- MLP head ----------------
__global__ void k_head(const float* __restrict__ pooled,
                       const float* __restrict__ fc1w, const float* __restrict__ fc1b,
                       const float* __restrict__ fc2w, const float* __restrict__ fc2b,
                       float* __restrict__ out) {
    int gph = blockIdx.x;
    int j = threadIdx.x;
    __shared__ float pl[64], hid[64];
    pl[j] = pooled[gph * 64 + j];
    __syncthreads();
    float s = fc1b[j];
    for (int k = 0; k < 64; k++) s += pl[k] * fc1w[j * 64 + k];
    hid[j] = fmaxf(s, 0.f);
    __syncthreads();
    if (j < 2) {
        float o = fc2b[j];
        for (int k = 0; k < 64; k++) o += hid[k] * fc2w[j * 64 + k];
        out[gph * 2 + j] = o;
    }
}

extern "C" void kernel_launch(void* const* d_in, const int* in_sizes, int n_in,
                              void* d_out, int out_size, void* d_ws, size_t ws_size,
                              hipStream_t stream) {
    const float* x    = (const float*)d_in[0];
    const int* ei     = (const int*)d_in[1];
    const int* batch  = (const int*)d_in[2];
    const float* w1l  = (const float*)d_in[3];
    const float* b1   = (const float*)d_in[4];
    const float* w1r  = (const float*)d_in[5];
    const float* bn1g = (const float*)d_in[6];
    const float* bn1b = (const float*)d_in[7];
    const float* w2l  = (const float*)d_in[8];
    const float* b2   = (const float*)d_in[9];
    const float* w2r  = (const float*)d_in[10];
    const float* bn2g = (const float*)d_in[11];
    const float* bn2b = (const float*)d_in[12];
    const float* w3l  = (const float*)d_in[13];
    const float* b3   = (const float*)d_in[14];
    const float* w3r  = (const float*)d_in[15];
    const float* bn3g = (const float*)d_in[16];
    const float* bn3b = (const float*)d_in[17];
    const float* fc1w = (const float*)d_in[18];
    const float* fc1b = (const float*)d_in[19];
    const float* fc2w = (const float*)d_in[20];
    const float* fc2b = (const float*)d_in[21];
    float* out = (float*)d_out;

    const int N = NN, E = NE;
    const int* srcp = ei;
    const int* dstp = ei + E;

    char* ws = (char*)d_ws;
    size_t off = 0;
    auto alloc = [&](size_t bytes) -> char* {
        char* p = ws + off;
        off += (bytes + 255) & ~(size_t)255;
        return p;
    };
    int* csr_src       = (int*)alloc(sizeof(int) * E);
    float* hB          = (float*)alloc(sizeof(float) * N * 64);   // pre-BN fp32
    __half* hH         = (__half*)alloc(sizeof(__half) * N * 64); // post-BN-ReLU fp16
    unsigned int* slab = (unsigned int*)alloc(sizeof(unsigned int) * (size_t)NBUK * BCAP);
    int* slab_cursor   = (int*)alloc(sizeof(int) * NBUK);
    int* bucket_base   = (int*)alloc(sizeof(int) * NBUK);
    int* row_ptr       = (int*)alloc(sizeof(int) * (N + 1));
    float* deg_inv     = (float*)alloc(sizeof(float) * N);
    float* stats       = (float*)alloc(sizeof(float) * 128);
    float* sb          = (float*)alloc(sizeof(float) * 128);
    float* pooled      = (float*)alloc(sizeof(float) * 64 * NG);

    const int NB16 = (N + 15) / 16;   // 6250
    const int NB32 = N / 32;          // 3125 (exact)

    // ---- CSR build ----
    hipMemsetAsync(slab_cursor, 0, sizeof(int) * NBUK, stream);
    k_scatter<<<256, 512, 0, stream>>>(srcp, dstp, slab_cursor, slab, E);
    k_bucket_scan<<<1, 1024, 0, stream>>>(slab_cursor, bucket_base, row_ptr);
    k_bucket_csr<<<NBUK, 256, 0, stream>>>(slab, slab_cursor, bucket_base, row_ptr, deg_inv, csr_src);

    // layer 1: x -> hB (pre-BN fp32), BN+ReLU -> hH (fp16)
    k_layer1<<<NB16, 256, 0, stream>>>(x, row_ptr, csr_src, deg_inv, w1l, b1, w1r, hB, N);
    hipMemsetAsync(stats, 0, sizeof(float) * 128, stream);
    k_stats<<<200, 256, 0, stream>>>(hB, stats, N);
    k_bnfinal<<<1, 64, 0, stream>>>(stats, bn1g, bn1b, sb, N);
    k_bnrelu_h<<<1024, 256, 0, stream>>>(hB, sb, hH, N);

    // layer 2
    k_sage<<<NB32, 512, 0, stream>>>(hH, row_ptr, csr_src, deg_inv, w2l, b2, w2r, hB, N);
    hipMemsetAsync(stats, 0, sizeof(float) * 128, stream);
    k_stats<<<200, 256, 0, stream>>>(hB, stats, N);
    k_bnfinal<<<1, 64, 0, stream>>>(stats, bn2g, bn2b, sb, N);
    k_bnrelu_h<<<1024, 256, 0, stream>>>(hB, sb, hH, N);

    // layer 3
    k_sage<<<NB32, 512, 0, stream>>>(hH, row_ptr, csr_src, deg_inv, w3l, b3, w3r, hB, N);
    hipMemsetAsync(stats, 0, sizeof(float) * 128, stream);
    k_stats<<<200, 256, 0, stream>>>(hB, stats, N);
    k_bnfinal<<<1, 64, 0, stream>>>(stats, bn3g, bn3b, sb, N);
    k_bnrelu_h<<<1024, 256, 0, stream>>>(hB, sb, hH, N);

    k_pool<<<NG, 256, 0, stream>>>(hH, batch, pooled, N);
    k_head<<<NG, 64, 0, stream>>>(pooled, fc1w, fc1b, fc2w, fc2b, out);
}

// Round 4
// 690.791 us; speedup vs baseline: 1.7891x; 1.0304x over previous
//
#include <hip/hip_runtime.h>
#include <hip/hip_fp16.h>

#define NN 100000
#define NE 3200000
#define NG 128
#define BN_EPS 1e-5f

#define NBUK 782          // ceil(100000 / 128)
#define BSHIFT 7          // bucket = dst >> 7 (128 nodes per bucket)
#define BCAP 6144         // slab capacity per bucket (mean 4096, +32 sigma)

typedef _Float16 h2v __attribute__((ext_vector_type(2)));

// stats layout: float[128][16] per layer (64-B stride -> atomics spread over 256 cache lines)
#define STATS_STRIDE 16
#define STATS_LAYER (128 * STATS_STRIDE)

// ---------------- bucketed edge scatter (counting-sort level 1) ----------------
// 512 blocks x 512 threads; block b owns edges [b*6250, (b+1)*6250)
__global__ void __launch_bounds__(512) k_scatter(
    const int* __restrict__ src, const int* __restrict__ dst,
    int* __restrict__ slab_cursor, unsigned int* __restrict__ slab, int E) {
    __shared__ int hist[NBUK + 2];
    __shared__ int cbase[NBUK + 2];
    int tid = threadIdx.x;
    int eBeg = blockIdx.x * 6250;
    int eEnd = min(eBeg + 6250, E);

    for (int t = tid; t < NBUK; t += 512) hist[t] = 0;
    __syncthreads();
    for (int e = eBeg + tid; e < eEnd; e += 512) {
        int b = dst[e] >> BSHIFT;
        atomicAdd(&hist[b], 1);
    }
    __syncthreads();
    for (int t = tid; t < NBUK; t += 512) {
        int c = hist[t];
        cbase[t] = (c > 0) ? atomicAdd(&slab_cursor[t], c) : 0;
    }
    __syncthreads();
    for (int t = tid; t < NBUK; t += 512) hist[t] = 0;
    __syncthreads();
    for (int e = eBeg + tid; e < eEnd; e += 512) {
        int d = dst[e];
        int b = d >> BSHIFT;
        int r = atomicAdd(&hist[b], 1);
        int pos = cbase[b] + r;
        if (pos < BCAP) slab[(size_t)b * BCAP + pos] = ((unsigned)src[e] << BSHIFT) | (unsigned)(d & 127);
    }
}

// ---------------- scan 782 bucket counts -> bucket CSR bases ----------------
__global__ void k_bucket_scan(const int* __restrict__ slab_cursor,
                              int* __restrict__ bucket_base, int* __restrict__ row_ptr) {
    __shared__ int sm[1024];
    int t = threadIdx.x;
    int c = (t < NBUK) ? min(slab_cursor[t], BCAP) : 0;
    sm[t] = c;
    __syncthreads();
    for (int off = 1; off < 1024; off <<= 1) {
        int add = (t >= off) ? sm[t - off] : 0;
        __syncthreads();
        sm[t] += add;
        __syncthreads();
    }
    if (t < NBUK) {
        bucket_base[t] = sm[t] - c;
        if (t == NBUK - 1) row_ptr[NN] = sm[t];
    }
}

// ---------------- per-bucket exact CSR build (counting-sort level 2) ----------------
__global__ void __launch_bounds__(512) k_bucket_csr(
    const unsigned int* __restrict__ slab, const int* __restrict__ slab_cursor,
    const int* __restrict__ bucket_base, int* __restrict__ row_ptr,
    float* __restrict__ deg_inv, int* __restrict__ csr_src) {
    __shared__ int sdeg[128];
    __shared__ int sscan[128];
    __shared__ int slcur[128];
    int tid = threadIdx.x;
    int b = blockIdx.x;
    int lo = b << BSHIFT;
    int cnt = min(slab_cursor[b], BCAP);
    const unsigned int* sl = slab + (size_t)b * BCAP;

    if (tid < 128) sdeg[tid] = 0;
    __syncthreads();
    for (int k = tid; k < cnt; k += 512) {
        atomicAdd(&sdeg[sl[k] & 127], 1);
    }
    __syncthreads();
    int v = (tid < 128) ? sdeg[tid] : 0;
    if (tid < 128) sscan[tid] = v;
    __syncthreads();
    for (int off = 1; off < 128; off <<= 1) {
        int add = 0;
        if (tid < 128 && tid >= off) add = sscan[tid - off];
        __syncthreads();
        if (tid < 128) sscan[tid] += add;
        __syncthreads();
    }
    int base = bucket_base[b];
    if (tid < 128) {
        int excl = sscan[tid] - v;
        int n = lo + tid;
        if (n < NN) {
            row_ptr[n] = base + excl;
            deg_inv[n] = 1.0f / fmaxf((float)v, 1.0f);
        }
        slcur[tid] = base + excl;
    }
    __syncthreads();
    for (int k = tid; k < cnt; k += 512) {
        unsigned int p = sl[k];
        int pos = atomicAdd(&slcur[p & 127], 1);
        csr_src[pos] = (int)(p >> BSHIFT);
    }
}

// ---------------- layer 1 (IN_DIM=4) + fused BN stats ----------------
__global__ void __launch_bounds__(256) k_layer1(
    const float* __restrict__ x, const int* __restrict__ row_ptr,
    const int* __restrict__ csr_src, const float* __restrict__ deg_inv,
    const float* __restrict__ w1l, const float* __restrict__ b1,
    const float* __restrict__ w1r, float* __restrict__ h_pre,
    float* __restrict__ stats, int N) {
    __shared__ float swl[256], swr[256], sb1[64];
    __shared__ float ssum[64], ssq[64];
    int tid = threadIdx.x;
    swl[tid] = w1l[tid];
    swr[tid] = w1r[tid];
    if (tid < 64) { sb1[tid] = b1[tid]; ssum[tid] = 0.f; ssq[tid] = 0.f; }
    __syncthreads();

    int g = tid & 15, ni = tid >> 4;
    int n = blockIdx.x * 16 + ni;   // N = 6250*16 exactly

    int r0 = row_ptr[n], r1 = row_ptr[n + 1];
    float4 acc = make_float4(0.f, 0.f, 0.f, 0.f);
    for (int e = r0 + g; e < r1; e += 16) {
        int s = csr_src[e];
        float4 xv = ((const float4*)x)[s];
        acc.x += xv.x; acc.y += xv.y; acc.z += xv.z; acc.w += xv.w;
    }
    for (int m = 1; m < 16; m <<= 1) {
        acc.x += __shfl_xor(acc.x, m);
        acc.y += __shfl_xor(acc.y, m);
        acc.z += __shfl_xor(acc.z, m);
        acc.w += __shfl_xor(acc.w, m);
    }
    float di = deg_inv[n];
    float ax = acc.x * di, ay = acc.y * di, az = acc.z * di, aw = acc.w * di;
    float4 xs = ((const float4*)x)[n];

    float4 o;
    float* op = &o.x;
#pragma unroll
    for (int m = 0; m < 4; m++) {
        int j = 4 * g + m;
        float s = sb1[j];
        s += ax * swl[j * 4 + 0] + ay * swl[j * 4 + 1] + az * swl[j * 4 + 2] + aw * swl[j * 4 + 3];
        s += xs.x * swr[j * 4 + 0] + xs.y * swr[j * 4 + 1] + xs.z * swr[j * 4 + 2] + xs.w * swr[j * 4 + 3];
        op[m] = s;
    }
    ((float4*)h_pre)[n * 16 + g] = o;

    // fused BN stats: reduce over the 4 node-groups within the wave, then LDS, then global
    float4 q = make_float4(o.x * o.x, o.y * o.y, o.z * o.z, o.w * o.w);
#pragma unroll
    for (int m = 16; m <= 32; m <<= 1) {
        o.x += __shfl_xor(o.x, m); o.y += __shfl_xor(o.y, m);
        o.z += __shfl_xor(o.z, m); o.w += __shfl_xor(o.w, m);
        q.x += __shfl_xor(q.x, m); q.y += __shfl_xor(q.y, m);
        q.z += __shfl_xor(q.z, m); q.w += __shfl_xor(q.w, m);
    }
    if ((tid & 48) == 0) {
        atomicAdd(&ssum[4 * g + 0], o.x); atomicAdd(&ssum[4 * g + 1], o.y);
        atomicAdd(&ssum[4 * g + 2], o.z); atomicAdd(&ssum[4 * g + 3], o.w);
        atomicAdd(&ssq[4 * g + 0], q.x);  atomicAdd(&ssq[4 * g + 1], q.y);
        atomicAdd(&ssq[4 * g + 2], q.z);  atomicAdd(&ssq[4 * g + 3], q.w);
    }
    __syncthreads();
    if (tid < 64) {
        atomicAdd(&stats[tid * STATS_STRIDE], ssum[tid]);
        atomicAdd(&stats[(64 + tid) * STATS_STRIDE], ssq[tid]);
    }
}

// ---------------- fused SAGE layer: prefetched fp16 gather + dot2 GEMM + BN stats ----------------
// 512 threads, 32 nodes/block. LDS 27.6 KB -> 4 blocks/CU (32 waves, 100% occ target).
__global__ void __launch_bounds__(512, 8) k_sage(
    const __half* __restrict__ h_in, const int* __restrict__ row_ptr,
    const int* __restrict__ csr_src, const float* __restrict__ deg_inv,
    const float* __restrict__ wl, const float* __restrict__ bl,
    const float* __restrict__ wr, float* __restrict__ h_pre,
    float* __restrict__ stats) {
    __shared__ h2v wl2s[32][68];   // [k-pair][out-channel]
    __shared__ h2v wr2s[32][68];
    __shared__ h2v tAh[32][36];    // [node][k-pair] aggregated neighbors
    __shared__ h2v tXh[32][36];    // [node][k-pair] self features
    __shared__ float ssum[64], ssq[64];
    int tid = threadIdx.x;
    for (int idx = tid; idx < 2048; idx += 512) {
        int j = idx & 63, kk = idx >> 6;
        float2 l = ((const float2*)wl)[j * 32 + kk];
        float2 r = ((const float2*)wr)[j * 32 + kk];
        wl2s[kk][j] = h2v{(_Float16)l.x, (_Float16)l.y};
        wr2s[kk][j] = h2v{(_Float16)r.x, (_Float16)r.y};
    }
    if (tid < 64) { ssum[tid] = 0.f; ssq[tid] = 0.f; }

    int g = tid & 15, ni = tid >> 4;      // ni in [0,32)
    int n = blockIdx.x * 32 + ni;         // N = 3125*32 exactly

    float ax = 0.f, ay = 0.f, az = 0.f, aw = 0.f;
    int r0 = row_ptr[n], r1 = row_ptr[n + 1];
    const uint2* tbl = (const uint2*)h_in;
    int e = r0;
    // 4-deep software pipeline: 4 independent gathers in flight per lane
    for (; e + 4 <= r1; e += 4) {
        int s0 = csr_src[e], s1 = csr_src[e + 1], s2 = csr_src[e + 2], s3 = csr_src[e + 3];
        uint2 v0 = tbl[(size_t)s0 * 16 + g];
        uint2 v1 = tbl[(size_t)s1 * 16 + g];
        uint2 v2 = tbl[(size_t)s2 * 16 + g];
        uint2 v3 = tbl[(size_t)s3 * 16 + g];
        float2 f;
        f = __half22float2(*(__half2*)&v0.x); ax += f.x; ay += f.y;
        f = __half22float2(*(__half2*)&v0.y); az += f.x; aw += f.y;
        f = __half22float2(*(__half2*)&v1.x); ax += f.x; ay += f.y;
        f = __half22float2(*(__half2*)&v1.y); az += f.x; aw += f.y;
        f = __half22float2(*(__half2*)&v2.x); ax += f.x; ay += f.y;
        f = __half22float2(*(__half2*)&v2.y); az += f.x; aw += f.y;
        f = __half22float2(*(__half2*)&v3.x); ax += f.x; ay += f.y;
        f = __half22float2(*(__half2*)&v3.y); az += f.x; aw += f.y;
    }
    for (; e < r1; ++e) {
        int s = csr_src[e];
        uint2 v = tbl[(size_t)s * 16 + g];
        float2 f;
        f = __half22float2(*(__half2*)&v.x); ax += f.x; ay += f.y;
        f = __half22float2(*(__half2*)&v.y); az += f.x; aw += f.y;
    }
    float di = deg_inv[n];
    uint2 rs = tbl[(size_t)n * 16 + g];
    ax *= di; ay *= di; az *= di; aw *= di;
    tAh[ni][2 * g]     = h2v{(_Float16)ax, (_Float16)ay};
    tAh[ni][2 * g + 1] = h2v{(_Float16)az, (_Float16)aw};
    *(uint2*)&tXh[ni][2 * g] = rs;   // raw halfs pass through
    __syncthreads();

    float4 o = ((const float4*)bl)[g];
#pragma unroll 4
    for (int kk = 0; kk < 32; kk++) {
        h2v a2 = tAh[ni][kk];
        h2v x2 = tXh[ni][kk];
        h2v l0 = wl2s[kk][4 * g + 0], l1 = wl2s[kk][4 * g + 1];
        h2v l2 = wl2s[kk][4 * g + 2], l3 = wl2s[kk][4 * g + 3];
        h2v r0v = wr2s[kk][4 * g + 0], r1v = wr2s[kk][4 * g + 1];
        h2v r2v = wr2s[kk][4 * g + 2], r3v = wr2s[kk][4 * g + 3];
#if __has_builtin(__builtin_amdgcn_fdot2)
        o.x = __builtin_amdgcn_fdot2(a2, l0, o.x, false);
        o.y = __builtin_amdgcn_fdot2(a2, l1, o.y, false);
        o.z = __builtin_amdgcn_fdot2(a2, l2, o.z, false);
        o.w = __builtin_amdgcn_fdot2(a2, l3, o.w, false);
        o.x = __builtin_amdgcn_fdot2(x2, r0v, o.x, false);
        o.y = __builtin_amdgcn_fdot2(x2, r1v, o.y, false);
        o.z = __builtin_amdgcn_fdot2(x2, r2v, o.z, false);
        o.w = __builtin_amdgcn_fdot2(x2, r3v, o.w, false);
#else
        float a0 = (float)a2.x, a1 = (float)a2.y, x0 = (float)x2.x, x1 = (float)x2.y;
        o.x += a0 * (float)l0.x + a1 * (float)l0.y + x0 * (float)r0v.x + x1 * (float)r0v.y;
        o.y += a0 * (float)l1.x + a1 * (float)l1.y + x0 * (float)r1v.x + x1 * (float)r1v.y;
        o.z += a0 * (float)l2.x + a1 * (float)l2.y + x0 * (float)r2v.x + x1 * (float)r2v.y;
        o.w += a0 * (float)l3.x + a1 * (float)l3.y + x0 * (float)r3v.x + x1 * (float)r3v.y;
#endif
    }
    ((float4*)h_pre)[(size_t)n * 16 + g] = o;

    // fused BN stats
    float4 q = make_float4(o.x * o.x, o.y * o.y, o.z * o.z, o.w * o.w);
#pragma unroll
    for (int m = 16; m <= 32; m <<= 1) {
        o.x += __shfl_xor(o.x, m); o.y += __shfl_xor(o.y, m);
        o.z += __shfl_xor(o.z, m); o.w += __shfl_xor(o.w, m);
        q.x += __shfl_xor(q.x, m); q.y += __shfl_xor(q.y, m);
        q.z += __shfl_xor(q.z, m); q.w += __shfl_xor(q.w, m);
    }
    if ((tid & 48) == 0) {
        atomicAdd(&ssum[4 * g + 0], o.x); atomicAdd(&ssum[4 * g + 1], o.y);
        atomicAdd(&ssum[4 * g + 2], o.z); atomicAdd(&ssum[4 * g + 3], o.w);
        atomicAdd(&ssq[4 * g + 0], q.x);  atomicAdd(&ssq[4 * g + 1], q.y);
        atomicAdd(&ssq[4 * g + 2], q.z);  atomicAdd(&ssq[4 * g + 3], q.w);
    }
    __syncthreads();
    if (tid < 64) {
        atomicAdd(&stats[tid * STATS_STRIDE], ssum[tid]);
        atomicAdd(&stats[(64 + tid) * STATS_STRIDE], ssq[tid]);
    }
}

// ---------------- BN(finalize inline)+ReLU -> fp16 table ----------------
__global__ void k_bnrelu_h(const float* __restrict__ h_pre, const float* __restrict__ stats,
                           const float* __restrict__ gamma, const float* __restrict__ beta,
                           __half* __restrict__ h, int N) {
    __shared__ float s_sc[64], s_bi[64];
    if (threadIdx.x < 64) {
        int c = threadIdx.x;
        float sum = stats[c * STATS_STRIDE];
        float ssq = stats[(64 + c) * STATS_STRIDE];
        float m = sum / (float)N;
        float var = ssq / (float)N - m * m;
        float sc = gamma[c] * rsqrtf(var + BN_EPS);
        s_sc[c] = sc;
        s_bi[c] = beta[c] - m * sc;
    }
    __syncthreads();
    int total = N * 16;
    for (int i = blockIdx.x * blockDim.x + threadIdx.x; i < total; i += gridDim.x * blockDim.x) {
        float4 v = ((const float4*)h_pre)[i];
        int c4 = (i & 15) * 4;
        v.x = fmaxf(v.x * s_sc[c4 + 0] + s_bi[c4 + 0], 0.f);
        v.y = fmaxf(v.y * s_sc[c4 + 1] + s_bi[c4 + 1], 0.f);
        v.z = fmaxf(v.z * s_sc[c4 + 2] + s_bi[c4 + 2], 0.f);
        v.w = fmaxf(v.w * s_sc[c4 + 3] + s_bi[c4 + 3], 0.f);
        __half2 p0 = __floats2half2_rn(v.x, v.y);
        __half2 p1 = __floats2half2_rn(v.z, v.w);
        uint2 o;
        o.x = *(unsigned int*)&p0;
        o.y = *(unsigned int*)&p1;
        ((uint2*)h)[i] = o;
    }
}

// ---------------- fused pool + MLP head ----------------
__global__ void k_poolhead(const __half* __restrict__ h, const int* __restrict__ batch,
                           const float* __restrict__ fc1w, const float* __restrict__ fc1b,
                           const float* __restrict__ fc2w, const float* __restrict__ fc2b,
                           float* __restrict__ out, int N) {
    int gph = blockIdx.x;
    int lo = 0, hi = N;
    while (lo < hi) { int mid = (lo + hi) >> 1; if (batch[mid] < gph) lo = mid + 1; else hi = mid; }
    int start = lo;
    hi = N;
    while (lo < hi) { int mid = (lo + hi) >> 1; if (batch[mid] < gph + 1) lo = mid + 1; else hi = mid; }
    int end = lo;

    int c = threadIdx.x & 63, w = threadIdx.x >> 6;
    float s = 0.f;
    for (int r = start + w; r < end; r += 4) s += __half2float(h[r * 64 + c]);
    __shared__ float sm[256];
    __shared__ float pl[64], hid[64];
    sm[threadIdx.x] = s;
    __syncthreads();
    if (threadIdx.x < 64) {
        float t = sm[c] + sm[64 + c] + sm[128 + c] + sm[192 + c];
        pl[c] = t / fmaxf((float)(end - start), 1.0f);
    }
    __syncthreads();
    if (threadIdx.x < 64) {
        int j = threadIdx.x;
        float v = fc1b[j];
        for (int k = 0; k < 64; k++) v += pl[k] * fc1w[j * 64 + k];
        hid[j] = fmaxf(v, 0.f);
    }
    __syncthreads();
    if (threadIdx.x < 2) {
        int j = threadIdx.x;
        float o = fc2b[j];
        for (int k = 0; k < 64; k++) o += hid[k] * fc2w[j * 64 + k];
        out[gph * 2 + j] = o;
    }
}

extern "C" void kernel_launch(void* const* d_in, const int* in_sizes, int n_in,
                              void* d_out, int out_size, void* d_ws, size_t ws_size,
                              hipStream_t stream) {
    const float* x    = (const float*)d_in[0];
    const int* ei     = (const int*)d_in[1];
    const int* batch  = (const int*)d_in[2];
    const float* w1l  = (const float*)d_in[3];
    const float* b1   = (const float*)d_in[4];
    const float* w1r  = (const float*)d_in[5];
    const float* bn1g = (const float*)d_in[6];
    const float* bn1b = (const float*)d_in[7];
    const float* w2l  = (const float*)d_in[8];
    const float* b2   = (const float*)d_in[9];
    const float* w2r  = (const float*)d_in[10];
    const float* bn2g = (const float*)d_in[11];
    const float* bn2b = (const float*)d_in[12];
    const float* w3l  = (const float*)d_in[13];
    const float* b3   = (const float*)d_in[14];
    const float* w3r  = (const float*)d_in[15];
    const float* bn3g = (const float*)d_in[16];
    const float* bn3b = (const float*)d_in[17];
    const float* fc1w = (const float*)d_in[18];
    const float* fc1b = (const float*)d_in[19];
    const float* fc2w = (const float*)d_in[20];
    const float* fc2b = (const float*)d_in[21];
    float* out = (float*)d_out;

    const int N = NN, E = NE;
    const int* srcp = ei;
    const int* dstp = ei + E;

    char* ws = (char*)d_ws;
    size_t off = 0;
    auto alloc = [&](size_t bytes) -> char* {
        char* p = ws + off;
        off += (bytes + 255) & ~(size_t)255;
        return p;
    };
    int* csr_src       = (int*)alloc(sizeof(int) * E);
    float* hB          = (float*)alloc(sizeof(float) * N * 64);   // pre-BN fp32
    __half* hH         = (__half*)alloc(sizeof(__half) * N * 64); // post-BN-ReLU fp16
    unsigned int* slab = (unsigned int*)alloc(sizeof(unsigned int) * (size_t)NBUK * BCAP);
    int* slab_cursor   = (int*)alloc(sizeof(int) * NBUK);
    int* bucket_base   = (int*)alloc(sizeof(int) * NBUK);
    int* row_ptr       = (int*)alloc(sizeof(int) * (N + 1));
    float* deg_inv     = (float*)alloc(sizeof(float) * N);
    float* stats       = (float*)alloc(sizeof(float) * 3 * STATS_LAYER);

    const int NB16 = (N + 15) / 16;   // 6250
    const int NB32 = N / 32;          // 3125 (exact)

    hipMemsetAsync(slab_cursor, 0, sizeof(int) * NBUK, stream);
    hipMemsetAsync(stats, 0, sizeof(float) * 3 * STATS_LAYER, stream);

    // ---- CSR build ----
    k_scatter<<<512, 512, 0, stream>>>(srcp, dstp, slab_cursor, slab, E);
    k_bucket_scan<<<1, 1024, 0, stream>>>(slab_cursor, bucket_base, row_ptr);
    k_bucket_csr<<<NBUK, 512, 0, stream>>>(slab, slab_cursor, bucket_base, row_ptr, deg_inv, csr_src);

    // layer 1: x -> hB (pre-BN fp32, stats fused), BN+ReLU -> hH (fp16)
    k_layer1<<<NB16, 256, 0, stream>>>(x, row_ptr, csr_src, deg_inv, w1l, b1, w1r, hB,
                                       stats + 0 * STATS_LAYER, N);
    k_bnrelu_h<<<1024, 256, 0, stream>>>(hB, stats + 0 * STATS_LAYER, bn1g, bn1b, hH, N);

    // layer 2
    k_sage<<<NB32, 512, 0, stream>>>(hH, row_ptr, csr_src, deg_inv, w2l, b2, w2r, hB,
                                     stats + 1 * STATS_LAYER);
    k_bnrelu_h<<<1024, 256, 0, stream>>>(hB, stats + 1 * STATS_LAYER, bn2g, bn2b, hH, N);

    // layer 3
    k_sage<<<NB32, 512, 0, stream>>>(hH, row_ptr, csr_src, deg_inv, w3l, b3, w3r, hB,
                                     stats + 2 * STATS_LAYER);
    k_bnrelu_h<<<1024, 256, 0, stream>>>(hB, stats + 2 * STATS_LAYER, bn3g, bn3b, hH, N);

    k_poolhead<<<NG, 256, 0, stream>>>(hH, batch, fc1w, fc1b, fc2w, fc2b, out, N);
}

// Round 5
// 469.349 us; speedup vs baseline: 2.6332x; 1.4718x over previous
//
#include <hip/hip_runtime.h>
#include <hip/hip_fp16.h>

#define NN 100000
#define NE 3200000
#define NG 128
#define BN_EPS 1e-5f

#define NBUK 782          // ceil(100000 / 128)
#define BSHIFT 7          // bucket = dst >> 7 (128 nodes per bucket)
#define BCAP 6144         // slab capacity per bucket (mean 4096, +32 sigma)

#define GRID_L1 2048      // persistent blocks, 8/CU
#define GRID_SG 1024      // persistent blocks, 4/CU (wave cap: 8 waves x 4 = 32/CU)
#define PBMAX 2048        // partial-buffer column stride

typedef _Float16 h2v __attribute__((ext_vector_type(2)));

// ---------------- bucketed edge scatter (counting-sort level 1) ----------------
__global__ void __launch_bounds__(512) k_scatter(
    const int* __restrict__ src, const int* __restrict__ dst,
    int* __restrict__ slab_cursor, unsigned int* __restrict__ slab, int E) {
    __shared__ int hist[NBUK + 2];
    __shared__ int cbase[NBUK + 2];
    int tid = threadIdx.x;
    int eBeg = blockIdx.x * 6250;
    int eEnd = min(eBeg + 6250, E);

    for (int t = tid; t < NBUK; t += 512) hist[t] = 0;
    __syncthreads();
    for (int e = eBeg + tid; e < eEnd; e += 512) {
        int b = dst[e] >> BSHIFT;
        atomicAdd(&hist[b], 1);
    }
    __syncthreads();
    for (int t = tid; t < NBUK; t += 512) {
        int c = hist[t];
        cbase[t] = (c > 0) ? atomicAdd(&slab_cursor[t], c) : 0;
    }
    __syncthreads();
    for (int t = tid; t < NBUK; t += 512) hist[t] = 0;
    __syncthreads();
    for (int e = eBeg + tid; e < eEnd; e += 512) {
        int d = dst[e];
        int b = d >> BSHIFT;
        int r = atomicAdd(&hist[b], 1);
        int pos = cbase[b] + r;
        if (pos < BCAP) slab[(size_t)b * BCAP + pos] = ((unsigned)src[e] << BSHIFT) | (unsigned)(d & 127);
    }
}

// ---------------- scan 782 bucket counts -> bucket CSR bases ----------------
__global__ void k_bucket_scan(const int* __restrict__ slab_cursor,
                              int* __restrict__ bucket_base, int* __restrict__ row_ptr) {
    __shared__ int sm[1024];
    int t = threadIdx.x;
    int c = (t < NBUK) ? min(slab_cursor[t], BCAP) : 0;
    sm[t] = c;
    __syncthreads();
    for (int off = 1; off < 1024; off <<= 1) {
        int add = (t >= off) ? sm[t - off] : 0;
        __syncthreads();
        sm[t] += add;
        __syncthreads();
    }
    if (t < NBUK) {
        bucket_base[t] = sm[t] - c;
        if (t == NBUK - 1) row_ptr[NN] = sm[t];
    }
}

// ---------------- per-bucket exact CSR build (counting-sort level 2) ----------------
__global__ void __launch_bounds__(512) k_bucket_csr(
    const unsigned int* __restrict__ slab, const int* __restrict__ slab_cursor,
    const int* __restrict__ bucket_base, int* __restrict__ row_ptr,
    float* __restrict__ deg_inv, int* __restrict__ csr_src) {
    __shared__ int sdeg[128];
    __shared__ int sscan[128];
    __shared__ int slcur[128];
    int tid = threadIdx.x;
    int b = blockIdx.x;
    int lo = b << BSHIFT;
    int cnt = min(slab_cursor[b], BCAP);
    const unsigned int* sl = slab + (size_t)b * BCAP;

    if (tid < 128) sdeg[tid] = 0;
    __syncthreads();
    for (int k = tid; k < cnt; k += 512) {
        atomicAdd(&sdeg[sl[k] & 127], 1);
    }
    __syncthreads();
    int v = (tid < 128) ? sdeg[tid] : 0;
    if (tid < 128) sscan[tid] = v;
    __syncthreads();
    for (int off = 1; off < 128; off <<= 1) {
        int add = 0;
        if (tid < 128 && tid >= off) add = sscan[tid - off];
        __syncthreads();
        if (tid < 128) sscan[tid] += add;
        __syncthreads();
    }
    int base = bucket_base[b];
    if (tid < 128) {
        int excl = sscan[tid] - v;
        int n = lo + tid;
        if (n < NN) {
            row_ptr[n] = base + excl;
            deg_inv[n] = 1.0f / fmaxf((float)v, 1.0f);
        }
        slcur[tid] = base + excl;
    }
    __syncthreads();
    for (int k = tid; k < cnt; k += 512) {
        unsigned int p = sl[k];
        int pos = atomicAdd(&slcur[p & 127], 1);
        csr_src[pos] = (int)(p >> BSHIFT);
    }
}

// ---------------- layer 1 (IN_DIM=4), persistent blocks, stats -> private partials ----------------
__global__ void __launch_bounds__(256) k_layer1(
    const float* __restrict__ x, const int* __restrict__ row_ptr,
    const int* __restrict__ csr_src, const float* __restrict__ deg_inv,
    const float* __restrict__ w1l, const float* __restrict__ b1,
    const float* __restrict__ w1r, float* __restrict__ h_pre,
    float* __restrict__ part, int N) {
    __shared__ float swl[256], swr[256], sb1[64];
    __shared__ float ssum[64], ssq[64];
    int tid = threadIdx.x;
    swl[tid] = w1l[tid];
    swr[tid] = w1r[tid];
    if (tid < 64) { sb1[tid] = b1[tid]; ssum[tid] = 0.f; ssq[tid] = 0.f; }
    __syncthreads();

    int g = tid & 15, ni = tid >> 4;
    const int ntiles = N / 16;   // 6250 exactly

    for (int tile = blockIdx.x; tile < ntiles; tile += gridDim.x) {
        int n = tile * 16 + ni;
        int r0 = row_ptr[n], r1 = row_ptr[n + 1];
        float4 acc = make_float4(0.f, 0.f, 0.f, 0.f);
        for (int e = r0 + g; e < r1; e += 16) {
            int s = csr_src[e];
            float4 xv = ((const float4*)x)[s];
            acc.x += xv.x; acc.y += xv.y; acc.z += xv.z; acc.w += xv.w;
        }
        for (int m = 1; m < 16; m <<= 1) {
            acc.x += __shfl_xor(acc.x, m);
            acc.y += __shfl_xor(acc.y, m);
            acc.z += __shfl_xor(acc.z, m);
            acc.w += __shfl_xor(acc.w, m);
        }
        float di = deg_inv[n];
        float ax = acc.x * di, ay = acc.y * di, az = acc.z * di, aw = acc.w * di;
        float4 xs = ((const float4*)x)[n];

        float4 o;
        float* op = &o.x;
#pragma unroll
        for (int m = 0; m < 4; m++) {
            int j = 4 * g + m;
            float s = sb1[j];
            s += ax * swl[j * 4 + 0] + ay * swl[j * 4 + 1] + az * swl[j * 4 + 2] + aw * swl[j * 4 + 3];
            s += xs.x * swr[j * 4 + 0] + xs.y * swr[j * 4 + 1] + xs.z * swr[j * 4 + 2] + xs.w * swr[j * 4 + 3];
            op[m] = s;
        }
        ((float4*)h_pre)[n * 16 + g] = o;

        float4 q = make_float4(o.x * o.x, o.y * o.y, o.z * o.z, o.w * o.w);
#pragma unroll
        for (int m = 16; m <= 32; m <<= 1) {
            o.x += __shfl_xor(o.x, m); o.y += __shfl_xor(o.y, m);
            o.z += __shfl_xor(o.z, m); o.w += __shfl_xor(o.w, m);
            q.x += __shfl_xor(q.x, m); q.y += __shfl_xor(q.y, m);
            q.z += __shfl_xor(q.z, m); q.w += __shfl_xor(q.w, m);
        }
        if ((tid & 48) == 0) {
            atomicAdd(&ssum[4 * g + 0], o.x); atomicAdd(&ssum[4 * g + 1], o.y);
            atomicAdd(&ssum[4 * g + 2], o.z); atomicAdd(&ssum[4 * g + 3], o.w);
            atomicAdd(&ssq[4 * g + 0], q.x);  atomicAdd(&ssq[4 * g + 1], q.y);
            atomicAdd(&ssq[4 * g + 2], q.z);  atomicAdd(&ssq[4 * g + 3], q.w);
        }
    }
    __syncthreads();
    if (tid < 64) {
        part[(2 * tid) * PBMAX + blockIdx.x]     = ssum[tid];
        part[(2 * tid + 1) * PBMAX + blockIdx.x] = ssq[tid];
    }
}

// ---------------- fused SAGE layer: persistent blocks, fp16 gather + dot2 GEMM ----------------
__global__ void __launch_bounds__(512, 8) k_sage(
    const __half* __restrict__ h_in, const int* __restrict__ row_ptr,
    const int* __restrict__ csr_src, const float* __restrict__ deg_inv,
    const float* __restrict__ wl, const float* __restrict__ bl,
    const float* __restrict__ wr, float* __restrict__ h_pre,
    float* __restrict__ part) {
    __shared__ h2v wl2s[32][68];   // [k-pair][out-channel]
    __shared__ h2v wr2s[32][68];
    __shared__ h2v tAh[32][36];
    __shared__ h2v tXh[32][36];
    __shared__ float ssum[64], ssq[64];
    int tid = threadIdx.x;
    for (int idx = tid; idx < 2048; idx += 512) {
        int j = idx & 63, kk = idx >> 6;
        float2 l = ((const float2*)wl)[j * 32 + kk];
        float2 r = ((const float2*)wr)[j * 32 + kk];
        wl2s[kk][j] = h2v{(_Float16)l.x, (_Float16)l.y};
        wr2s[kk][j] = h2v{(_Float16)r.x, (_Float16)r.y};
    }
    if (tid < 64) { ssum[tid] = 0.f; ssq[tid] = 0.f; }
    __syncthreads();

    int g = tid & 15, ni = tid >> 4;      // ni in [0,32)
    const uint2* tbl = (const uint2*)h_in;
    const int ntiles = NN / 32;           // 3125 exactly

    for (int tile = blockIdx.x; tile < ntiles; tile += gridDim.x) {
        int n = tile * 32 + ni;
        float ax = 0.f, ay = 0.f, az = 0.f, aw = 0.f;
        int r0 = row_ptr[n], r1 = row_ptr[n + 1];
        int e = r0;
        for (; e + 4 <= r1; e += 4) {
            int s0 = csr_src[e], s1 = csr_src[e + 1], s2 = csr_src[e + 2], s3 = csr_src[e + 3];
            uint2 v0 = tbl[(size_t)s0 * 16 + g];
            uint2 v1 = tbl[(size_t)s1 * 16 + g];
            uint2 v2 = tbl[(size_t)s2 * 16 + g];
            uint2 v3 = tbl[(size_t)s3 * 16 + g];
            float2 f;
            f = __half22float2(*(__half2*)&v0.x); ax += f.x; ay += f.y;
            f = __half22float2(*(__half2*)&v0.y); az += f.x; aw += f.y;
            f = __half22float2(*(__half2*)&v1.x); ax += f.x; ay += f.y;
            f = __half22float2(*(__half2*)&v1.y); az += f.x; aw += f.y;
            f = __half22float2(*(__half2*)&v2.x); ax += f.x; ay += f.y;
            f = __half22float2(*(__half2*)&v2.y); az += f.x; aw += f.y;
            f = __half22float2(*(__half2*)&v3.x); ax += f.x; ay += f.y;
            f = __half22float2(*(__half2*)&v3.y); az += f.x; aw += f.y;
        }
        for (; e < r1; ++e) {
            int s = csr_src[e];
            uint2 v = tbl[(size_t)s * 16 + g];
            float2 f;
            f = __half22float2(*(__half2*)&v.x); ax += f.x; ay += f.y;
            f = __half22float2(*(__half2*)&v.y); az += f.x; aw += f.y;
        }
        float di = deg_inv[n];
        uint2 rs = tbl[(size_t)n * 16 + g];
        ax *= di; ay *= di; az *= di; aw *= di;
        tAh[ni][2 * g]     = h2v{(_Float16)ax, (_Float16)ay};
        tAh[ni][2 * g + 1] = h2v{(_Float16)az, (_Float16)aw};
        *(uint2*)&tXh[ni][2 * g] = rs;
        __syncthreads();

        float4 o = ((const float4*)bl)[g];
#pragma unroll 4
        for (int kk = 0; kk < 32; kk++) {
            h2v a2 = tAh[ni][kk];
            h2v x2 = tXh[ni][kk];
            h2v l0 = wl2s[kk][4 * g + 0], l1 = wl2s[kk][4 * g + 1];
            h2v l2 = wl2s[kk][4 * g + 2], l3 = wl2s[kk][4 * g + 3];
            h2v r0v = wr2s[kk][4 * g + 0], r1v = wr2s[kk][4 * g + 1];
            h2v r2v = wr2s[kk][4 * g + 2], r3v = wr2s[kk][4 * g + 3];
#if __has_builtin(__builtin_amdgcn_fdot2)
            o.x = __builtin_amdgcn_fdot2(a2, l0, o.x, false);
            o.y = __builtin_amdgcn_fdot2(a2, l1, o.y, false);
            o.z = __builtin_amdgcn_fdot2(a2, l2, o.z, false);
            o.w = __builtin_amdgcn_fdot2(a2, l3, o.w, false);
            o.x = __builtin_amdgcn_fdot2(x2, r0v, o.x, false);
            o.y = __builtin_amdgcn_fdot2(x2, r1v, o.y, false);
            o.z = __builtin_amdgcn_fdot2(x2, r2v, o.z, false);
            o.w = __builtin_amdgcn_fdot2(x2, r3v, o.w, false);
#else
            float a0 = (float)a2.x, a1 = (float)a2.y, x0 = (float)x2.x, x1 = (float)x2.y;
            o.x += a0 * (float)l0.x + a1 * (float)l0.y + x0 * (float)r0v.x + x1 * (float)r0v.y;
            o.y += a0 * (float)l1.x + a1 * (float)l1.y + x0 * (float)r1v.x + x1 * (float)r1v.y;
            o.z += a0 * (float)l2.x + a1 * (float)l2.y + x0 * (float)r2v.x + x1 * (float)r2v.y;
            o.w += a0 * (float)l3.x + a1 * (float)l3.y + x0 * (float)r3v.x + x1 * (float)r3v.y;
#endif
        }
        ((float4*)h_pre)[(size_t)n * 16 + g] = o;

        float4 q = make_float4(o.x * o.x, o.y * o.y, o.z * o.z, o.w * o.w);
#pragma unroll
        for (int m = 16; m <= 32; m <<= 1) {
            o.x += __shfl_xor(o.x, m); o.y += __shfl_xor(o.y, m);
            o.z += __shfl_xor(o.z, m); o.w += __shfl_xor(o.w, m);
            q.x += __shfl_xor(q.x, m); q.y += __shfl_xor(q.y, m);
            q.z += __shfl_xor(q.z, m); q.w += __shfl_xor(q.w, m);
        }
        if ((tid & 48) == 0) {
            atomicAdd(&ssum[4 * g + 0], o.x); atomicAdd(&ssum[4 * g + 1], o.y);
            atomicAdd(&ssum[4 * g + 2], o.z); atomicAdd(&ssum[4 * g + 3], o.w);
            atomicAdd(&ssq[4 * g + 0], q.x);  atomicAdd(&ssq[4 * g + 1], q.y);
            atomicAdd(&ssq[4 * g + 2], q.z);  atomicAdd(&ssq[4 * g + 3], q.w);
        }
        __syncthreads();   // protect tAh/tXh for next tile
    }
    if (tid < 64) {
        part[(2 * tid) * PBMAX + blockIdx.x]     = ssum[tid];
        part[(2 * tid + 1) * PBMAX + blockIdx.x] = ssq[tid];
    }
}

// ---------------- reduce partials -> BN scale/bias ----------------
// 64 blocks x 256 threads; block c reduces rows 2c (sum) and 2c+1 (sumsq)
__global__ void k_reduce_sb(const float* __restrict__ part, int PB,
                            const float* __restrict__ gamma, const float* __restrict__ beta,
                            float* __restrict__ sbv, int N) {
    int c = blockIdx.x;
    float s = 0.f, q = 0.f;
    for (int b = threadIdx.x; b < PB; b += 256) {
        s += part[(2 * c) * PBMAX + b];
        q += part[(2 * c + 1) * PBMAX + b];
    }
    __shared__ float rs[256], rq[256];
    rs[threadIdx.x] = s;
    rq[threadIdx.x] = q;
    __syncthreads();
    for (int off = 128; off > 0; off >>= 1) {
        if (threadIdx.x < off) {
            rs[threadIdx.x] += rs[threadIdx.x + off];
            rq[threadIdx.x] += rq[threadIdx.x + off];
        }
        __syncthreads();
    }
    if (threadIdx.x == 0) {
        float m = rs[0] / (float)N;
        float var = rq[0] / (float)N - m * m;
        float sc = gamma[c] * rsqrtf(var + BN_EPS);
        sbv[c]      = sc;
        sbv[64 + c] = beta[c] - m * sc;
    }
}

// ---------------- BN+ReLU -> fp16 table ----------------
__global__ void k_bnrelu_h(const float* __restrict__ h_pre, const float* __restrict__ sbv,
                           __half* __restrict__ h, int N) {
    __shared__ float s_sc[64], s_bi[64];
    if (threadIdx.x < 64) {
        s_sc[threadIdx.x] = sbv[threadIdx.x];
        s_bi[threadIdx.x] = sbv[64 + threadIdx.x];
    }
    __syncthreads();
    int total = N * 16;
    for (int i = blockIdx.x * blockDim.x + threadIdx.x; i < total; i += gridDim.x * blockDim.x) {
        float4 v = ((const float4*)h_pre)[i];
        int c4 = (i & 15) * 4;
        v.x = fmaxf(v.x * s_sc[c4 + 0] + s_bi[c4 + 0], 0.f);
        v.y = fmaxf(v.y * s_sc[c4 + 1] + s_bi[c4 + 1], 0.f);
        v.z = fmaxf(v.z * s_sc[c4 + 2] + s_bi[c4 + 2], 0.f);
        v.w = fmaxf(v.w * s_sc[c4 + 3] + s_bi[c4 + 3], 0.f);
        __half2 p0 = __floats2half2_rn(v.x, v.y);
        __half2 p1 = __floats2half2_rn(v.z, v.w);
        uint2 o;
        o.x = *(unsigned int*)&p0;
        o.y = *(unsigned int*)&p1;
        ((uint2*)h)[i] = o;
    }
}

// ---------------- fused pool + MLP head ----------------
__global__ void k_poolhead(const __half* __restrict__ h, const int* __restrict__ batch,
                           const float* __restrict__ fc1w, const float* __restrict__ fc1b,
                           const float* __restrict__ fc2w, const float* __restrict__ fc2b,
                           float* __restrict__ out, int N) {
    int gph = blockIdx.x;
    int lo = 0, hi = N;
    while (lo < hi) { int mid = (lo + hi) >> 1; if (batch[mid] < gph) lo = mid + 1; else hi = mid; }
    int start = lo;
    hi = N;
    while (lo < hi) { int mid = (lo + hi) >> 1; if (batch[mid] < gph + 1) lo = mid + 1; else hi = mid; }
    int end = lo;

    int c = threadIdx.x & 63, w = threadIdx.x >> 6;
    float s = 0.f;
    for (int r = start + w; r < end; r += 4) s += __half2float(h[r * 64 + c]);
    __shared__ float sm[256];
    __shared__ float pl[64], hid[64];
    sm[threadIdx.x] = s;
    __syncthreads();
    if (threadIdx.x < 64) {
        float t = sm[c] + sm[64 + c] + sm[128 + c] + sm[192 + c];
        pl[c] = t / fmaxf((float)(end - start), 1.0f);
    }
    __syncthreads();
    if (threadIdx.x < 64) {
        int j = threadIdx.x;
        float v = fc1b[j];
        for (int k = 0; k < 64; k++) v += pl[k] * fc1w[j * 64 + k];
        hid[j] = fmaxf(v, 0.f);
    }
    __syncthreads();
    if (threadIdx.x < 2) {
        int j = threadIdx.x;
        float o = fc2b[j];
        for (int k = 0; k < 64; k++) o += hid[k] * fc2w[j * 64 + k];
        out[gph * 2 + j] = o;
    }
}

extern "C" void kernel_launch(void* const* d_in, const int* in_sizes, int n_in,
                              void* d_out, int out_size, void* d_ws, size_t ws_size,
                              hipStream_t stream) {
    const float* x    = (const float*)d_in[0];
    const int* ei     = (const int*)d_in[1];
    const int* batch  = (const int*)d_in[2];
    const float* w1l  = (const float*)d_in[3];
    const float* b1   = (const float*)d_in[4];
    const float* w1r  = (const float*)d_in[5];
    const float* bn1g = (const float*)d_in[6];
    const float* bn1b = (const float*)d_in[7];
    const float* w2l  = (const float*)d_in[8];
    const float* b2   = (const float*)d_in[9];
    const float* w2r  = (const float*)d_in[10];
    const float* bn2g = (const float*)d_in[11];
    const float* bn2b = (const float*)d_in[12];
    const float* w3l  = (const float*)d_in[13];
    const float* b3   = (const float*)d_in[14];
    const float* w3r  = (const float*)d_in[15];
    const float* bn3g = (const float*)d_in[16];
    const float* bn3b = (const float*)d_in[17];
    const float* fc1w = (const float*)d_in[18];
    const float* fc1b = (const float*)d_in[19];
    const float* fc2w = (const float*)d_in[20];
    const float* fc2b = (const float*)d_in[21];
    float* out = (float*)d_out;

    const int N = NN, E = NE;
    const int* srcp = ei;
    const int* dstp = ei + E;

    char* ws = (char*)d_ws;
    size_t off = 0;
    auto alloc = [&](size_t bytes) -> char* {
        char* p = ws + off;
        off += (bytes + 255) & ~(size_t)255;
        return p;
    };
    int* csr_src       = (int*)alloc(sizeof(int) * E);
    float* hB          = (float*)alloc(sizeof(float) * N * 64);   // pre-BN fp32
    __half* hH         = (__half*)alloc(sizeof(__half) * N * 64); // post-BN-ReLU fp16
    unsigned int* slab = (unsigned int*)alloc(sizeof(unsigned int) * (size_t)NBUK * BCAP);
    int* slab_cursor   = (int*)alloc(sizeof(int) * NBUK);
    int* bucket_base   = (int*)alloc(sizeof(int) * NBUK);
    int* row_ptr       = (int*)alloc(sizeof(int) * (N + 1));
    float* deg_inv     = (float*)alloc(sizeof(float) * N);
    float* part        = (float*)alloc(sizeof(float) * 128 * PBMAX);
    float* sbv         = (float*)alloc(sizeof(float) * 128);

    hipMemsetAsync(slab_cursor, 0, sizeof(int) * NBUK, stream);

    // ---- CSR build ----
    k_scatter<<<512, 512, 0, stream>>>(srcp, dstp, slab_cursor, slab, E);
    k_bucket_scan<<<1, 1024, 0, stream>>>(slab_cursor, bucket_base, row_ptr);
    k_bucket_csr<<<NBUK, 512, 0, stream>>>(slab, slab_cursor, bucket_base, row_ptr, deg_inv, csr_src);

    // layer 1: x -> hB (pre-BN fp32, stats partials fused), reduce, BN+ReLU -> hH (fp16)
    k_layer1<<<GRID_L1, 256, 0, stream>>>(x, row_ptr, csr_src, deg_inv, w1l, b1, w1r, hB, part, N);
    k_reduce_sb<<<64, 256, 0, stream>>>(part, GRID_L1, bn1g, bn1b, sbv, N);
    k_bnrelu_h<<<1024, 256, 0, stream>>>(hB, sbv, hH, N);

    // layer 2
    k_sage<<<GRID_SG, 512, 0, stream>>>(hH, row_ptr, csr_src, deg_inv, w2l, b2, w2r, hB, part);
    k_reduce_sb<<<64, 256, 0, stream>>>(part, GRID_SG, bn2g, bn2b, sbv, N);
    k_bnrelu_h<<<1024, 256, 0, stream>>>(hB, sbv, hH, N);

    // layer 3
    k_sage<<<GRID_SG, 512, 0, stream>>>(hH, row_ptr, csr_src, deg_inv, w3l, b3, w3r, hB, part);
    k_reduce_sb<<<64, 256, 0, stream>>>(part, GRID_SG, bn3g, bn3b, sbv, N);
    k_bnrelu_h<<<1024, 256, 0, stream>>>(hB, sbv, hH, N);

    k_poolhead<<<NG, 256, 0, stream>>>(hH, batch, fc1w, fc1b, fc2w, fc2b, out, N);
}